// Round 3
// baseline (447.106 us; speedup 1.0000x reference)
//
#include <hip/hip_runtime.h>
#include <math.h>

constexpr int B = 4, C = 64, H = 96, W = 96;
constexpr int KT = 9;           // 3x3 taps
constexpr int OFFC = 18;        // 2*KT offset channels
constexpr int HW = H * W;
constexpr int PAD = 4;          // zero halo; |offset| ~<1.5 in practice, clamp covers rest
constexpr int HP = H + 2 * PAD, WP = W + 2 * PAD;   // 104 x 104
constexpr int HPWP = HP * WP;

// ---------------------------------------------------------------------------
// Zero-halo padded copy of x: xpad[B*C][HP][WP]
// ---------------------------------------------------------------------------
__global__ void pad_x(const float* __restrict__ x, float* __restrict__ xpad) {
    int i = blockIdx.x * 256 + threadIdx.x;
    const int total = B * C * HPWP;
    if (i >= total) return;
    int col = i % WP;
    int t = i / WP;
    int row = t % HP;
    int bc = t / HP;
    int h = row - PAD, w = col - PAD;
    float v = 0.0f;
    if (h >= 0 && h < H && w >= 0 && w < W) v = x[(size_t)bc * HW + h * W + w];
    xpad[i] = v;
}

// ---------------------------------------------------------------------------
// Weight transposes:
//   wofft[c][t][oc] = w_off[oc][c][t]   (64*9*18)
//   wdct [k][c][o]  = w_dc [o][c][k]    (9*64*64)
// ---------------------------------------------------------------------------
__global__ void prep_w(const float* __restrict__ w_off,
                       const float* __restrict__ w_dc,
                       float* __restrict__ wofft,
                       float* __restrict__ wdct) {
    int i = blockIdx.x * 256 + threadIdx.x;
    if (i < C * KT * OFFC) {
        int oc = i % OFFC;
        int t2 = i / OFFC;
        int tap = t2 % KT;
        int c = t2 / KT;
        wofft[i] = w_off[((size_t)oc * C + c) * KT + tap];
    }
    if (i < KT * C * C) {
        int o = i % C;
        int t2 = i / C;
        int c = t2 % C;
        int k = t2 / C;
        wdct[i] = w_dc[((size_t)o * C + c) * KT + k];
    }
}

// ---------------------------------------------------------------------------
// Offset conv on padded x: thread = pixel, 9 offset channels (2 groups).
// Per input channel: 9 independent window loads, then 81 FMA. No predication.
// ---------------------------------------------------------------------------
__global__ void offset_conv3(const float* __restrict__ xpad,
                             const float* __restrict__ wofft,
                             const float* __restrict__ b_off,
                             float* __restrict__ off) {
    const int pix = blockIdx.x * 256 + threadIdx.x;
    const int ocg = blockIdx.y * 9;
    const int w = pix % W;
    int t = pix / W;
    const int h = t % H;
    const int b_u = __builtin_amdgcn_readfirstlane(t / H);

    const float* xb = xpad + (size_t)b_u * C * HPWP + (h + PAD - 1) * WP + (w + PAD - 1);

    float acc[9];
    #pragma unroll
    for (int j = 0; j < 9; ++j) acc[j] = b_off[ocg + j];

    const float* wp = wofft + ocg;   // [c][t][18]
    #pragma unroll 2
    for (int c = 0; c < C; ++c) {
        float win[9];
        #pragma unroll
        for (int t2 = 0; t2 < 9; ++t2) win[t2] = xb[(t2 / 3) * WP + (t2 % 3)];
        #pragma unroll
        for (int t2 = 0; t2 < 9; ++t2) {
            #pragma unroll
            for (int j = 0; j < 9; ++j)
                acc[j] = fmaf(win[t2], wp[t2 * OFFC + j], acc[j]);
        }
        xb += HPWP;
        wp += KT * OFFC;
    }

    float* ob = off + ((size_t)b_u * OFFC + ocg) * HW + h * W + w;
    #pragma unroll
    for (int j = 0; j < 9; ++j) ob[j * HW] = acc[j];
}

// ---------------------------------------------------------------------------
// Deformable conv, LDS-shared samples.
// Block = 256 thr = 4 waves, 64 pixels (lane=pixel). Wave wid:
//   - samples channels [16*wid, 16*wid+16) into smem[c][pix]
//   - contracts all 64 c into output channels [16*wid, 16*wid+16)
// Tap k+1's 64 gather loads are issued before tap k's contraction (latency
// hides under ~2300 cyc of FMA).
// ---------------------------------------------------------------------------
__global__ void deform3(const float* __restrict__ xpad,
                        const float* __restrict__ off,
                        const float* __restrict__ wdct,
                        const float* __restrict__ b_dc,
                        float* __restrict__ out) {
    const int lane = threadIdx.x & 63;
    const int wid = threadIdx.x >> 6;
    const int og = wid << 4;
    const int pix = blockIdx.x * 64 + lane;
    const int w = pix % W;
    const int t = pix / W;
    const int h = t % H;
    const int b_u = __builtin_amdgcn_readfirstlane(t / H);

    __shared__ float smem[64][64];   // [c][pix] — 2 lanes/bank everywhere: free

    const float* xb = xpad + ((size_t)b_u * C + og) * HPWP;  // my 16 sample channels
    const float* offb = off + (size_t)b_u * OFFC * HW + h * W + w;

    float acc[16];
    #pragma unroll
    for (int o = 0; o < 16; ++o) acc[o] = b_dc[og + o];

    float v0[16], v1[16], v2[16], v3[16];
    float w00, w01, w10, w11;
    float dy = offb[0];
    float dx = offb[HW];

    auto sample = [&](int ky, int kx) {
        const float py = (float)(h + ky - 1) + dy;
        const float px = (float)(w + kx - 1) + dx;
        const float y0f = floorf(py);
        const float x0f = floorf(px);
        const float ly = py - y0f;
        const float lx = px - x0f;
        int y0 = (int)y0f;
        int x0 = (int)x0f;
        y0 = min(max(y0, -PAD), H + PAD - 2);   // clamp lands in zero halo
        x0 = min(max(x0, -PAD), W + PAD - 2);
        const int base = (y0 + PAD) * WP + (x0 + PAD);
        const float a11 = ly * lx;
        w11 = a11;
        w10 = ly - a11;
        w01 = lx - a11;
        w00 = 1.0f - ly - lx + a11;
        const float* xc = xb + base;
        #pragma unroll
        for (int j = 0; j < 16; ++j) {      // 64 independent gather loads
            v0[j] = xc[0];
            v1[j] = xc[1];
            v2[j] = xc[WP];
            v3[j] = xc[WP + 1];
            xc += HPWP;
        }
    };

    sample(0, 0);                     // tap 0 loads in flight
    const float* wk = wdct + og;      // [k][c][o], advance 4096/tap
    int ky = 0, kx = 0;

    for (int k = 0; k < 9; ++k) {
        if (k < 8) {                  // prefetch next tap's offsets
            dy = offb[(2 * k + 2) * HW];
            dx = offb[(2 * k + 3) * HW];
        }
        __syncthreads();              // all waves done reading previous tap
        #pragma unroll
        for (int j = 0; j < 16; ++j) {
            smem[og + j][lane] = v0[j] * w00 + v1[j] * w01 + v2[j] * w10 + v3[j] * w11;
        }
        __syncthreads();              // tap k staged

        if (k < 8) {                  // issue tap k+1 loads: hide under contraction
            kx++;
            if (kx == 3) { kx = 0; ky++; }
            sample(ky, kx);
        }

        // contract tap k: 64 ds_read + 1024 FMA, uniform scalar weights
        #pragma unroll 1
        for (int cc = 0; cc < C; cc += 8) {
            #pragma unroll
            for (int c8 = 0; c8 < 8; ++c8) {
                const float s = smem[cc + c8][lane];
                #pragma unroll
                for (int o = 0; o < 16; ++o)
                    acc[o] = fmaf(s, wk[(cc + c8) * C + o], acc[o]);
            }
        }
        wk += C * C;
    }

    float* ob = out + ((size_t)b_u * C + og) * HW + h * W + w;
    #pragma unroll
    for (int o = 0; o < 16; ++o) ob[o * HW] = acc[o];
}

// ---------------------------------------------------------------------------
extern "C" void kernel_launch(void* const* d_in, const int* in_sizes, int n_in,
                              void* d_out, int out_size, void* d_ws, size_t ws_size,
                              hipStream_t stream) {
    const float* x     = (const float*)d_in[0];
    const float* w_off = (const float*)d_in[1];
    const float* b_off = (const float*)d_in[2];
    const float* w_dc  = (const float*)d_in[3];
    const float* b_dc  = (const float*)d_in[4];
    float* out = (float*)d_out;

    float* off   = (float*)d_ws;                 // B*18*HW       = 663552 f
    float* wdct  = off + (size_t)B * OFFC * HW;  // 9*64*64       = 36864 f
    float* wofft = wdct + KT * C * C;            // 64*9*18       = 10368 f
    float* xpad  = wofft + C * KT * OFFC;        // B*C*HP*WP     = 2768896 f (~11 MB)

    {   // padded copy
        const int total = B * C * HPWP;
        pad_x<<<(total + 255) / 256, 256, 0, stream>>>(x, xpad);
    }
    {   // weight transposes
        prep_w<<<(KT * C * C + 255) / 256, 256, 0, stream>>>(w_off, w_dc, wofft, wdct);
    }
    {   // offset conv
        dim3 grid(B * HW / 256, 2);
        offset_conv3<<<grid, 256, 0, stream>>>(xpad, wofft, b_off, off);
    }
    {   // deformable conv
        deform3<<<B * HW / 64, 256, 0, stream>>>(xpad, off, wdct, b_dc, out);
    }
}

// Round 4
// 157.990 us; speedup vs baseline: 2.8300x; 2.8300x over previous
//
#include <hip/hip_runtime.h>
#include <math.h>

constexpr int B = 4, C = 64, H = 96, W = 96;
constexpr int KT = 9;           // 3x3 taps
constexpr int OFFC = 18;        // 2*KT offset channels
constexpr int HW = H * W;
constexpr int PAD = 4;          // zero halo; clamp lands out-of-image samples in zeros
constexpr int HP = H + 2 * PAD, WP = W + 2 * PAD;   // 104 x 104
constexpr int HPWP = HP * WP;

// ---------------------------------------------------------------------------
// Zero-halo padded copy of x: xpad[B*C][HP][WP]
// ---------------------------------------------------------------------------
__global__ __launch_bounds__(256) void pad_x(const float* __restrict__ x,
                                             float* __restrict__ xpad) {
    int i = blockIdx.x * 256 + threadIdx.x;
    const int total = B * C * HPWP;
    if (i >= total) return;
    int col = i % WP;
    int t = i / WP;
    int row = t % HP;
    int bc = t / HP;
    int h = row - PAD, w = col - PAD;
    float v = 0.0f;
    if (h >= 0 && h < H && w >= 0 && w < W) v = x[(size_t)bc * HW + h * W + w];
    xpad[i] = v;
}

// ---------------------------------------------------------------------------
// Weight transposes:
//   wofft[c][t][oc] = w_off[oc][c][t]   (64*9*18)
//   wdct [k][c][o]  = w_dc [o][c][k]    (9*64*64)
// ---------------------------------------------------------------------------
__global__ __launch_bounds__(256) void prep_w(const float* __restrict__ w_off,
                                              const float* __restrict__ w_dc,
                                              float* __restrict__ wofft,
                                              float* __restrict__ wdct) {
    int i = blockIdx.x * 256 + threadIdx.x;
    if (i < C * KT * OFFC) {
        int oc = i % OFFC;
        int t2 = i / OFFC;
        int tap = t2 % KT;
        int c = t2 / KT;
        wofft[i] = w_off[((size_t)oc * C + c) * KT + tap];
    }
    if (i < KT * C * C) {
        int o = i % C;
        int t2 = i / C;
        int c = t2 % C;
        int k = t2 / C;
        wdct[i] = w_dc[((size_t)o * C + c) * KT + k];
    }
}

// ---------------------------------------------------------------------------
// Offset conv on padded x: thread = pixel, 9 offset channels (2 groups).
// ---------------------------------------------------------------------------
__global__ __launch_bounds__(256, 2) void offset_conv3(
        const float* __restrict__ xpad,
        const float* __restrict__ wofft,
        const float* __restrict__ b_off,
        float* __restrict__ off) {
    const int pix = blockIdx.x * 256 + threadIdx.x;
    const int ocg = blockIdx.y * 9;
    const int w = pix % W;
    int t = pix / W;
    const int h = t % H;
    const int b_u = __builtin_amdgcn_readfirstlane(t / H);

    const float* xb = xpad + (size_t)b_u * C * HPWP + (h + PAD - 1) * WP + (w + PAD - 1);

    float acc[9];
    #pragma unroll
    for (int j = 0; j < 9; ++j) acc[j] = b_off[ocg + j];

    const float* wp = wofft + ocg;   // [c][t][18]
    #pragma unroll 2
    for (int c = 0; c < C; ++c) {
        float win[9];
        #pragma unroll
        for (int t2 = 0; t2 < 9; ++t2) win[t2] = xb[(t2 / 3) * WP + (t2 % 3)];
        #pragma unroll
        for (int t2 = 0; t2 < 9; ++t2) {
            #pragma unroll
            for (int j = 0; j < 9; ++j)
                acc[j] = fmaf(win[t2], wp[t2 * OFFC + j], acc[j]);
        }
        xb += HPWP;
        wp += KT * OFFC;
    }

    float* ob = off + ((size_t)b_u * OFFC + ocg) * HW + h * W + w;
    #pragma unroll
    for (int j = 0; j < 9; ++j) ob[j * HW] = acc[j];
}

// ---------------------------------------------------------------------------
// Deformable conv, LDS-shared samples.
// Block = 256 thr = 4 waves, 64 pixels (lane=pixel). Wave wid:
//   - samples channels [16*wid, 16*wid+16) into smem[c][pix]
//   - contracts all 64 c into output channels [16*wid, 16*wid+16)
// __launch_bounds__(256,2): VGPR cap 256 — staging arrays MUST stay in regs
// (round-3 lesson: default bounds capped VGPR at 64 -> 760 MB scratch spill).
// ---------------------------------------------------------------------------
__global__ __launch_bounds__(256, 2) void deform3(
        const float* __restrict__ xpad,
        const float* __restrict__ off,
        const float* __restrict__ wdct,
        const float* __restrict__ b_dc,
        float* __restrict__ out) {
    const int lane = threadIdx.x & 63;
    const int wid = __builtin_amdgcn_readfirstlane(threadIdx.x >> 6);
    const int og = wid << 4;
    const int pix = blockIdx.x * 64 + lane;
    const int w = pix % W;
    const int t = pix / W;
    const int h = t % H;
    const int b_u = __builtin_amdgcn_readfirstlane(t / H);

    __shared__ float smem[64][64];   // [c][pix] — 2 lanes/bank: free

    const float* xb = xpad + ((size_t)b_u * C + og) * HPWP;  // my 16 sample channels
    const float* offb = off + (size_t)b_u * OFFC * HW + h * W + w;

    float acc[16];
    #pragma unroll
    for (int o = 0; o < 16; ++o) acc[o] = b_dc[og + o];

    float v0[16], v1[16], v2[16], v3[16];
    float w00, w01, w10, w11;
    float dy = offb[0];
    float dx = offb[HW];

    auto sample = [&](int ky, int kx) {
        const float py = (float)(h + ky - 1) + dy;
        const float px = (float)(w + kx - 1) + dx;
        const float y0f = floorf(py);
        const float x0f = floorf(px);
        const float ly = py - y0f;
        const float lx = px - x0f;
        int y0 = (int)y0f;
        int x0 = (int)x0f;
        y0 = min(max(y0, -PAD), H + PAD - 2);   // clamp lands in zero halo
        x0 = min(max(x0, -PAD), W + PAD - 2);
        const int base = (y0 + PAD) * WP + (x0 + PAD);
        const float a11 = ly * lx;
        w11 = a11;
        w10 = ly - a11;
        w01 = lx - a11;
        w00 = 1.0f - ly - lx + a11;
        const float* xc = xb + base;
        #pragma unroll
        for (int j = 0; j < 16; ++j) {      // 64 independent gather loads
            v0[j] = xc[0];
            v1[j] = xc[1];
            v2[j] = xc[WP];
            v3[j] = xc[WP + 1];
            xc += HPWP;
        }
    };

    sample(0, 0);                     // tap 0 loads in flight
    const float* wk = wdct + og;      // [k][c][o], advance 4096/tap
    int ky = 0, kx = 0;

    for (int k = 0; k < 9; ++k) {
        if (k < 8) {                  // prefetch next tap's offsets
            dy = offb[(2 * k + 2) * HW];
            dx = offb[(2 * k + 3) * HW];
        }
        __syncthreads();              // all waves done reading previous tap
        #pragma unroll
        for (int j = 0; j < 16; ++j) {
            smem[og + j][lane] = v0[j] * w00 + v1[j] * w01 + v2[j] * w10 + v3[j] * w11;
        }
        __syncthreads();              // tap k staged

        if (k < 8) {                  // issue tap k+1 loads: hide under contraction
            kx++;
            if (kx == 3) { kx = 0; ky++; }
            sample(ky, kx);
        }

        // contract tap k: 64 ds_read + 1024 FMA, wave-uniform weights (s_load)
        #pragma unroll 1
        for (int cc = 0; cc < C; cc += 8) {
            #pragma unroll
            for (int c8 = 0; c8 < 8; ++c8) {
                const float s = smem[cc + c8][lane];
                #pragma unroll
                for (int o = 0; o < 16; ++o)
                    acc[o] = fmaf(s, wk[(cc + c8) * C + o], acc[o]);
            }
        }
        wk += C * C;
    }

    float* ob = out + ((size_t)b_u * C + og) * HW + h * W + w;
    #pragma unroll
    for (int o = 0; o < 16; ++o) ob[o * HW] = acc[o];
}

// ---------------------------------------------------------------------------
extern "C" void kernel_launch(void* const* d_in, const int* in_sizes, int n_in,
                              void* d_out, int out_size, void* d_ws, size_t ws_size,
                              hipStream_t stream) {
    const float* x     = (const float*)d_in[0];
    const float* w_off = (const float*)d_in[1];
    const float* b_off = (const float*)d_in[2];
    const float* w_dc  = (const float*)d_in[3];
    const float* b_dc  = (const float*)d_in[4];
    float* out = (float*)d_out;

    float* off   = (float*)d_ws;                 // B*18*HW       = 663552 f
    float* wdct  = off + (size_t)B * OFFC * HW;  // 9*64*64       = 36864 f
    float* wofft = wdct + KT * C * C;            // 64*9*18       = 10368 f
    float* xpad  = wofft + C * KT * OFFC;        // B*C*HP*WP     = 2768896 f (~11 MB)

    {   // padded copy
        const int total = B * C * HPWP;
        pad_x<<<(total + 255) / 256, 256, 0, stream>>>(x, xpad);
    }
    {   // weight transposes
        prep_w<<<(KT * C * C + 255) / 256, 256, 0, stream>>>(w_off, w_dc, wofft, wdct);
    }
    {   // offset conv
        dim3 grid(B * HW / 256, 2);
        offset_conv3<<<grid, 256, 0, stream>>>(xpad, wofft, b_off, off);
    }
    {   // deformable conv
        deform3<<<B * HW / 64, 256, 0, stream>>>(xpad, off, wdct, b_dc, out);
    }
}

// Round 5
// 147.828 us; speedup vs baseline: 3.0245x; 1.0687x over previous
//
#include <hip/hip_runtime.h>
#include <math.h>

constexpr int B = 4, C = 64, H = 96, W = 96;
constexpr int KT = 9;           // 3x3 taps
constexpr int OFFC = 18;        // 2*KT offset channels
constexpr int HW = H * W;
constexpr int PAD = 4;          // zero halo; clamp lands out-of-image samples in zeros
constexpr int HP = H + 2 * PAD, WP = W + 2 * PAD;   // 104 x 104
constexpr int HPWP = HP * WP;

// ---------------------------------------------------------------------------
// Zero-halo padded copy of x: xpad[B*C][HP][WP]
// ---------------------------------------------------------------------------
__global__ __launch_bounds__(256) void pad_x(const float* __restrict__ x,
                                             float* __restrict__ xpad) {
    int i = blockIdx.x * 256 + threadIdx.x;
    const int total = B * C * HPWP;
    if (i >= total) return;
    int col = i % WP;
    int t = i / WP;
    int row = t % HP;
    int bc = t / HP;
    int h = row - PAD, w = col - PAD;
    float v = 0.0f;
    if (h >= 0 && h < H && w >= 0 && w < W) v = x[(size_t)bc * HW + h * W + w];
    xpad[i] = v;
}

// ---------------------------------------------------------------------------
// Weight transposes:
//   wofft[c][t][oc] = w_off[oc][c][t]   (64*9*18)
//   wdct [k][c][o]  = w_dc [o][c][k]    (9*64*64)
// ---------------------------------------------------------------------------
__global__ __launch_bounds__(256) void prep_w(const float* __restrict__ w_off,
                                              const float* __restrict__ w_dc,
                                              float* __restrict__ wofft,
                                              float* __restrict__ wdct) {
    int i = blockIdx.x * 256 + threadIdx.x;
    if (i < C * KT * OFFC) {
        int oc = i % OFFC;
        int t2 = i / OFFC;
        int tap = t2 % KT;
        int c = t2 / KT;
        wofft[i] = w_off[((size_t)oc * C + c) * KT + tap];
    }
    if (i < KT * C * C) {
        int o = i % C;
        int t2 = i / C;
        int c = t2 % C;
        int k = t2 / C;
        wdct[i] = w_dc[((size_t)o * C + c) * KT + k];
    }
}

// ---------------------------------------------------------------------------
// Offset conv on padded x: thread = pixel, 9 offset channels (2 groups).
// 1D grid with chunked XCD swizzle (288 blocks = 8 XCD x 36).
// ---------------------------------------------------------------------------
__global__ __launch_bounds__(256, 2) void offset_conv3(
        const float* __restrict__ xpad,
        const float* __restrict__ wofft,
        const float* __restrict__ b_off,
        float* __restrict__ off) {
    const int bid = blockIdx.x;                       // 0..287
    const int fid = (bid & 7) * 36 + (bid >> 3);      // chunked XCD swizzle
    const int tile = fid % 144;
    const int ocg = (fid / 144) * 9;
    const int pix = tile * 256 + threadIdx.x;
    const int w = pix % W;
    int t = pix / W;
    const int h = t % H;
    const int b_u = __builtin_amdgcn_readfirstlane(t / H);

    const float* xb = xpad + (size_t)b_u * C * HPWP + (h + PAD - 1) * WP + (w + PAD - 1);

    float acc[9];
    #pragma unroll
    for (int j = 0; j < 9; ++j) acc[j] = b_off[ocg + j];

    const float* wp = wofft + ocg;   // [c][t][18]
    #pragma unroll 2
    for (int c = 0; c < C; ++c) {
        float win[9];
        #pragma unroll
        for (int t2 = 0; t2 < 9; ++t2) win[t2] = xb[(t2 / 3) * WP + (t2 % 3)];
        #pragma unroll
        for (int t2 = 0; t2 < 9; ++t2) {
            #pragma unroll
            for (int j = 0; j < 9; ++j)
                acc[j] = fmaf(win[t2], wp[t2 * OFFC + j], acc[j]);
        }
        xb += HPWP;
        wp += KT * OFFC;
    }

    float* ob = off + ((size_t)b_u * OFFC + ocg) * HW + h * W + w;
    #pragma unroll
    for (int j = 0; j < 9; ++j) ob[j * HW] = acc[j];
}

// ---------------------------------------------------------------------------
// Deformable conv, LDS-shared samples.
// Block = 256 thr = 4 waves, 64 pixels (lane=pixel). Wave wid:
//   - samples channels [16*wid, 16*wid+16) into smem[c][pix]
//   - contracts all 64 c into output channels [16*wid, 16*wid+16)
// sched_barrier(0) after sample(): round-4 lesson — without it the scheduler
// sinks the 64 gather loads to the loop bottom (VGPR 60) and exposes full
// memory latency every tap. Chunked XCD swizzle: each XCD works a contiguous
// ~1.5 MB xpad slice that fits its private 4 MB L2.
// ---------------------------------------------------------------------------
__global__ __launch_bounds__(256, 2) void deform3(
        const float* __restrict__ xpad,
        const float* __restrict__ off,
        const float* __restrict__ wdct,
        const float* __restrict__ b_dc,
        float* __restrict__ out) {
    const int lane = threadIdx.x & 63;
    const int wid = __builtin_amdgcn_readfirstlane(threadIdx.x >> 6);
    const int og = wid << 4;
    const int bid = blockIdx.x;                       // 0..575
    const int fid = (bid & 7) * 72 + (bid >> 3);      // chunked XCD swizzle
    const int pix = fid * 64 + lane;
    const int w = pix % W;
    const int t = pix / W;
    const int h = t % H;
    const int b_u = __builtin_amdgcn_readfirstlane(t / H);

    __shared__ float smem[64][64];   // [c][pix] — 2 lanes/bank: free

    const float* xb = xpad + ((size_t)b_u * C + og) * HPWP;  // my 16 sample channels
    const float* offb = off + (size_t)b_u * OFFC * HW + h * W + w;

    float acc[16];
    #pragma unroll
    for (int o = 0; o < 16; ++o) acc[o] = b_dc[og + o];

    float v0[16], v1[16], v2[16], v3[16];
    float w00, w01, w10, w11;
    float dy = offb[0];
    float dx = offb[HW];

    auto sample = [&](int ky, int kx) {
        const float py = (float)(h + ky - 1) + dy;
        const float px = (float)(w + kx - 1) + dx;
        const float y0f = floorf(py);
        const float x0f = floorf(px);
        const float ly = py - y0f;
        const float lx = px - x0f;
        int y0 = (int)y0f;
        int x0 = (int)x0f;
        y0 = min(max(y0, -PAD), H + PAD - 2);   // clamp lands in zero halo
        x0 = min(max(x0, -PAD), W + PAD - 2);
        const int base = (y0 + PAD) * WP + (x0 + PAD);
        const float a11 = ly * lx;
        w11 = a11;
        w10 = ly - a11;
        w01 = lx - a11;
        w00 = 1.0f - ly - lx + a11;
        const float* xc = xb + base;
        #pragma unroll
        for (int j = 0; j < 16; ++j) {      // 64 independent gather loads
            v0[j] = xc[0];
            v1[j] = xc[1];
            v2[j] = xc[WP];
            v3[j] = xc[WP + 1];
            xc += HPWP;
        }
    };

    sample(0, 0);                     // tap 0 loads in flight
    const float* wk = wdct + og;      // [k][c][o], advance 4096/tap
    int ky = 0, kx = 0;

    for (int k = 0; k < 9; ++k) {
        if (k < 8) {                  // prefetch next tap's offsets
            dy = offb[(2 * k + 2) * HW];
            dx = offb[(2 * k + 3) * HW];
        }
        __syncthreads();              // all waves done reading previous tap
        #pragma unroll
        for (int j = 0; j < 16; ++j) {
            smem[og + j][lane] = v0[j] * w00 + v1[j] * w01 + v2[j] * w10 + v3[j] * w11;
        }
        __syncthreads();              // tap k staged

        if (k < 8) {                  // issue tap k+1 loads: hide under contraction
            kx++;
            if (kx == 3) { kx = 0; ky++; }
            sample(ky, kx);
        }
        // Fence: loads above may NOT be scheduled below this point (they'd
        // lose their 2048-cycle FMA cover — round-4 regression).
        __builtin_amdgcn_sched_barrier(0);

        // contract tap k: 64 ds_read + 1024 FMA, wave-uniform weights (s_load)
        #pragma unroll 1
        for (int cc = 0; cc < C; cc += 8) {
            #pragma unroll
            for (int c8 = 0; c8 < 8; ++c8) {
                const float s = smem[cc + c8][lane];
                #pragma unroll
                for (int o = 0; o < 16; ++o)
                    acc[o] = fmaf(s, wk[(cc + c8) * C + o], acc[o]);
            }
        }
        wk += C * C;
    }

    float* ob = out + ((size_t)b_u * C + og) * HW + h * W + w;
    #pragma unroll
    for (int o = 0; o < 16; ++o) ob[o * HW] = acc[o];
}

// ---------------------------------------------------------------------------
extern "C" void kernel_launch(void* const* d_in, const int* in_sizes, int n_in,
                              void* d_out, int out_size, void* d_ws, size_t ws_size,
                              hipStream_t stream) {
    const float* x     = (const float*)d_in[0];
    const float* w_off = (const float*)d_in[1];
    const float* b_off = (const float*)d_in[2];
    const float* w_dc  = (const float*)d_in[3];
    const float* b_dc  = (const float*)d_in[4];
    float* out = (float*)d_out;

    float* off   = (float*)d_ws;                 // B*18*HW       = 663552 f
    float* wdct  = off + (size_t)B * OFFC * HW;  // 9*64*64       = 36864 f
    float* wofft = wdct + KT * C * C;            // 64*9*18       = 10368 f
    float* xpad  = wofft + C * KT * OFFC;        // B*C*HP*WP     = 2768896 f (~11 MB)

    {   // padded copy
        const int total = B * C * HPWP;
        pad_x<<<(total + 255) / 256, 256, 0, stream>>>(x, xpad);
    }
    {   // weight transposes
        prep_w<<<(KT * C * C + 255) / 256, 256, 0, stream>>>(w_off, w_dc, wofft, wdct);
    }
    {   // offset conv: 288 blocks (8 XCD x 36), swizzled inside
        offset_conv3<<<288, 256, 0, stream>>>(xpad, wofft, b_off, off);
    }
    {   // deformable conv: 576 blocks (8 XCD x 72), swizzled inside
        deform3<<<576, 256, 0, stream>>>(xpad, off, wdct, b_dc, out);
    }
}

// Round 6
// 98.457 us; speedup vs baseline: 4.5411x; 1.5014x over previous
//
#include <hip/hip_runtime.h>
#include <math.h>

constexpr int B = 4, C = 64, H = 96, W = 96;
constexpr int KT = 9;           // 3x3 taps
constexpr int OFFC = 18;        // 2*KT offset channels
constexpr int HW = H * W;
constexpr int PAD = 4;          // zero halo; clamp semantics exactly match reference
constexpr int HP = H + 2 * PAD, WP = W + 2 * PAD;   // 104 x 104
constexpr int HPWP = HP * WP;

// ---------------------------------------------------------------------------
// Fused prep: zero-halo pad of x, weight transposes, bias-init of off and out.
// Grid covers B*C*HPWP = 2,768,896 exactly (10816 blocks x 256) — the largest
// of the five jobs; smaller jobs are index-guarded.
//   wofft[c][t][oc] = w_off[oc][c][t]
//   wdct [k][c][o]  = w_dc [o][c][k]
// off/out get their bias here; conv kernels accumulate partials atomically.
// ---------------------------------------------------------------------------
__global__ __launch_bounds__(256) void prep_all(
        const float* __restrict__ x,
        const float* __restrict__ w_off,
        const float* __restrict__ w_dc,
        const float* __restrict__ b_off,
        const float* __restrict__ b_dc,
        float* __restrict__ xpad,
        float* __restrict__ wofft,
        float* __restrict__ wdct,
        float* __restrict__ off,
        float* __restrict__ out) {
    const int i = blockIdx.x * 256 + threadIdx.x;
    {   // pad: every thread does one element
        int col = i % WP;
        int t = i / WP;
        int row = t % HP;
        int bc = t / HP;
        int h = row - PAD, w = col - PAD;
        float v = 0.0f;
        if (h >= 0 && h < H && w >= 0 && w < W) v = x[(size_t)bc * HW + h * W + w];
        xpad[i] = v;
    }
    if (i < B * C * HW) out[i] = b_dc[(i / HW) % C];          // 2,359,296
    if (i < B * OFFC * HW) off[i] = b_off[(i / HW) % OFFC];   //   663,552
    if (i < C * KT * OFFC) {
        int oc = i % OFFC;
        int t2 = i / OFFC;
        wofft[i] = w_off[((size_t)(i % OFFC) * 0 + (size_t)oc * C + t2 / KT) * KT + t2 % KT];
    }
    if (i < KT * C * C) {
        int o = i % C;
        int t2 = i / C;
        int c = t2 % C;
        int k = t2 / C;
        wdct[i] = w_dc[((size_t)o * C + c) * KT + k];
    }
}

// ---------------------------------------------------------------------------
// Offset conv, c-split x4 for TLP: grid (288, 4). Each block: 256 pixels,
// 9 offset channels, 16 input channels; partials atomicAdd'd onto bias-
// initialized off. 1152 blocks = 4.5 blocks/CU.
// ---------------------------------------------------------------------------
__global__ __launch_bounds__(256, 4) void offset_conv4(
        const float* __restrict__ xpad,
        const float* __restrict__ wofft,
        float* __restrict__ off) {
    const int bid = blockIdx.x;                       // 0..287
    const int fid = (bid & 7) * 36 + (bid >> 3);      // chunked XCD swizzle
    const int tile = fid % 144;
    const int ocg = (fid / 144) * 9;
    const int c0 = blockIdx.y * 16;
    const int pix = tile * 256 + threadIdx.x;
    const int w = pix % W;
    int t = pix / W;
    const int h = t % H;
    const int b_u = __builtin_amdgcn_readfirstlane(t / H);

    const float* xb = xpad + ((size_t)b_u * C + c0) * HPWP + (h + PAD - 1) * WP + (w + PAD - 1);

    float acc[9];
    #pragma unroll
    for (int j = 0; j < 9; ++j) acc[j] = 0.0f;

    const float* wp = wofft + (size_t)c0 * KT * OFFC + ocg;   // [c][t][18]
    #pragma unroll 2
    for (int c = 0; c < 16; ++c) {
        float win[9];
        #pragma unroll
        for (int t2 = 0; t2 < 9; ++t2) win[t2] = xb[(t2 / 3) * WP + (t2 % 3)];
        #pragma unroll
        for (int t2 = 0; t2 < 9; ++t2) {
            #pragma unroll
            for (int j = 0; j < 9; ++j)
                acc[j] = fmaf(win[t2], wp[t2 * OFFC + j], acc[j]);
        }
        xb += HPWP;
        wp += KT * OFFC;
    }

    float* ob = off + ((size_t)b_u * OFFC + ocg) * HW + h * W + w;
    #pragma unroll
    for (int j = 0; j < 9; ++j) unsafeAtomicAdd(&ob[j * HW], acc[j]);
}

// ---------------------------------------------------------------------------
// Deformable conv, c-split x2 for TLP: grid (576, 2). Block = 4 waves,
// 64 pixels (lane=pixel), 32 input channels (cb = 32*blockIdx.y).
// Wave wid samples its 8 channels into smem, contracts all 32 block-channels
// into output channels [16*wid, +16); partials atomicAdd'd onto bias-
// initialized out. 1152 blocks = 4.5 blocks/CU; 32-load staging batches fit
// registers (round-5 lesson: 64-load batches got collapsed, VGPR 60).
// ---------------------------------------------------------------------------
__global__ __launch_bounds__(256, 4) void deform4(
        const float* __restrict__ xpad,
        const float* __restrict__ off,
        const float* __restrict__ wdct,
        float* __restrict__ out) {
    const int lane = threadIdx.x & 63;
    const int wid = __builtin_amdgcn_readfirstlane(threadIdx.x >> 6);
    const int og = wid << 4;
    const int cb = blockIdx.y << 5;                   // 0 or 32
    const int bid = blockIdx.x;                       // 0..575
    const int fid = (bid & 7) * 72 + (bid >> 3);      // chunked XCD swizzle
    const int pix = fid * 64 + lane;
    const int w = pix % W;
    const int t = pix / W;
    const int h = t % H;
    const int b_u = __builtin_amdgcn_readfirstlane(t / H);

    __shared__ float smem[32][64];   // [c-cb][pix] — 2 lanes/bank: free

    const float* xb = xpad + ((size_t)b_u * C + cb + (wid << 3)) * HPWP;  // my 8 channels
    const float* offb = off + (size_t)b_u * OFFC * HW + h * W + w;

    float acc[16];
    #pragma unroll
    for (int o = 0; o < 16; ++o) acc[o] = 0.0f;

    float v0[8], v1[8], v2[8], v3[8];
    float w00, w01, w10, w11;
    float dy = offb[0];
    float dx = offb[HW];

    auto sample = [&](int ky, int kx) {
        const float py = (float)(h + ky - 1) + dy;
        const float px = (float)(w + kx - 1) + dx;
        const float y0f = floorf(py);
        const float x0f = floorf(px);
        const float ly = py - y0f;
        const float lx = px - x0f;
        int y0 = (int)y0f;
        int x0 = (int)x0f;
        y0 = min(max(y0, -PAD), H + PAD - 2);   // clamp lands in zero halo
        x0 = min(max(x0, -PAD), W + PAD - 2);
        const int base = (y0 + PAD) * WP + (x0 + PAD);
        const float a11 = ly * lx;
        w11 = a11;
        w10 = ly - a11;
        w01 = lx - a11;
        w00 = 1.0f - ly - lx + a11;
        const float* xc = xb + base;
        #pragma unroll
        for (int j = 0; j < 8; ++j) {       // 32 independent gather loads
            v0[j] = xc[0];
            v1[j] = xc[1];
            v2[j] = xc[WP];
            v3[j] = xc[WP + 1];
            xc += HPWP;
        }
    };

    sample(0, 0);                     // tap 0 loads in flight
    const float* wk = wdct + cb * C + og;   // [k][c][o]
    int ky = 0, kx = 0;

    for (int k = 0; k < 9; ++k) {
        if (k < 8) {                  // prefetch next tap's offsets
            dy = offb[(2 * k + 2) * HW];
            dx = offb[(2 * k + 3) * HW];
        }
        __syncthreads();              // all waves done reading previous tap
        #pragma unroll
        for (int j = 0; j < 8; ++j) {
            smem[(wid << 3) + j][lane] = v0[j] * w00 + v1[j] * w01 + v2[j] * w10 + v3[j] * w11;
        }
        __syncthreads();              // tap k staged

        if (k < 8) {                  // issue tap k+1 loads: hide under contraction
            kx++;
            if (kx == 3) { kx = 0; ky++; }
            sample(ky, kx);
        }
        __builtin_amdgcn_sched_barrier(0);  // loads may not sink into the FMA block

        // contract tap k: 32 ds_read + 512 FMA, wave-uniform weights (s_load)
        #pragma unroll 1
        for (int cc = 0; cc < 32; cc += 8) {
            #pragma unroll
            for (int c8 = 0; c8 < 8; ++c8) {
                const float s = smem[cc + c8][lane];
                #pragma unroll
                for (int o = 0; o < 16; ++o)
                    acc[o] = fmaf(s, wk[(cc + c8) * C + o], acc[o]);
            }
        }
        wk += C * C;
    }

    float* ob = out + ((size_t)b_u * C + og) * HW + h * W + w;
    #pragma unroll
    for (int o = 0; o < 16; ++o) unsafeAtomicAdd(&ob[o * HW], acc[o]);
}

// ---------------------------------------------------------------------------
extern "C" void kernel_launch(void* const* d_in, const int* in_sizes, int n_in,
                              void* d_out, int out_size, void* d_ws, size_t ws_size,
                              hipStream_t stream) {
    const float* x     = (const float*)d_in[0];
    const float* w_off = (const float*)d_in[1];
    const float* b_off = (const float*)d_in[2];
    const float* w_dc  = (const float*)d_in[3];
    const float* b_dc  = (const float*)d_in[4];
    float* out = (float*)d_out;

    float* off   = (float*)d_ws;                 // B*18*HW   = 663552 f
    float* wdct  = off + (size_t)B * OFFC * HW;  // 9*64*64   = 36864 f
    float* wofft = wdct + KT * C * C;            // 64*9*18   = 10368 f
    float* xpad  = wofft + C * KT * OFFC;        // B*C*HP*WP = 2768896 f (~11 MB)

    {   // fused pad + transpose + bias-init (covers B*C*HPWP exactly)
        prep_all<<<B * C * HPWP / 256, 256, 0, stream>>>(
            x, w_off, w_dc, b_off, b_dc, xpad, wofft, wdct, off, out);
    }
    {   // offset conv: (288 tiles*ocg) x 4 c-quarters = 1152 blocks
        dim3 grid(288, 4);
        offset_conv4<<<grid, 256, 0, stream>>>(xpad, wofft, off);
    }
    {   // deformable conv: 576 pixel-tiles x 2 c-halves = 1152 blocks
        dim3 grid(576, 2);
        deform4<<<grid, 256, 0, stream>>>(xpad, off, wdct, out);
    }
}

// Round 7
// 55.922 us; speedup vs baseline: 7.9952x; 1.7606x over previous
//
#include <hip/hip_runtime.h>
#include <math.h>

typedef _Float16 half8 __attribute__((ext_vector_type(8)));
typedef float f32x4 __attribute__((ext_vector_type(4)));

constexpr int B = 4, C = 64, H = 96, W = 96;
constexpr int KT = 9, OFFC = 18;
constexpr int HW = H * W;
constexpr int PAD = 4;                      // zero halo; offsets are small (|off|<~0.5)
constexpr int HP = H + 2 * PAD, WP = W + 2 * PAD;   // 104 x 104
constexpr int HPWP = HP * WP;
constexpr int NTILE = B * HW / 64;          // 576 tiles of 64 pixels
constexpr int WDF_HALFS = 4 * KT * 2 * 64 * 8;   // 36864  (wave,tap,ks,lane,j)
constexpr int WOF_HALFS = 2 * KT * 2 * 64 * 8;   // 18432  (mfrag,tap,ks,lane,j)

// ---------------------------------------------------------------------------
// Prep: f16 zero-halo pad of x + MFMA A-fragment weight layouts.
//  wdf[wave][tap][ks][lane][j] = f16( w_dc[o=wave*16+(l&15)][c=ks*32+(l>>4)*8+j][tap] )
//  wof[mf  ][tap][ks][lane][j] = f16( w_off[oc=mf*16+(l&15)][c=...][tap] ), 0 for oc>=18
// A-frag layout for mfma_f32_16x16x32_f16: lane l holds A[m=l&15][k=(l>>4)*8+j].
// ---------------------------------------------------------------------------
__global__ __launch_bounds__(256) void prep(
        const float* __restrict__ x, const float* __restrict__ w_off,
        const float* __restrict__ w_dc,
        _Float16* __restrict__ xpad, _Float16* __restrict__ wdf,
        _Float16* __restrict__ wof) {
    const int i = blockIdx.x * 256 + threadIdx.x;   // grid covers B*C*HPWP exactly
    {   // pad
        int col = i % WP; int t = i / WP; int row = t % HP; int bc = t / HP;
        int h = row - PAD, w = col - PAD;
        float v = 0.f;
        if (h >= 0 && h < H && w >= 0 && w < W) v = x[(size_t)bc * HW + h * W + w];
        xpad[i] = (_Float16)v;
    }
    if (i < WDF_HALFS) {
        int wave = i / 9216, r = i % 9216;
        int tap = r / 1024, l = (r >> 3) & 63, j = i & 7;
        int ks = (r >> 9) & 1;
        int o = wave * 16 + (l & 15);
        int c = ks * 32 + ((l >> 4) << 3) + j;
        wdf[i] = (_Float16)w_dc[((size_t)o * C + c) * KT + tap];
    }
    if (i < WOF_HALFS) {
        int mf = i / 9216, r = i % 9216;
        int tap = r / 1024, l = (r >> 3) & 63, j = i & 7;
        int ks = (r >> 9) & 1;
        int oc = mf * 16 + (l & 15);
        int c = ks * 32 + ((l >> 4) << 3) + j;
        wof[i] = (oc < OFFC) ? (_Float16)w_off[((size_t)oc * C + c) * KT + tap]
                             : (_Float16)0.f;
    }
}

// ---------------------------------------------------------------------------
// Shared LDS layout: S[row=pix 0..63][c 0..63] f16, 128 B rows, XOR-swizzled
// at 16B-slot granularity: slot' = slot ^ (row & 7)  (T2 pattern; conflict-free
// b128 writes (per-wave c-strip) and b128 B-fragment reads).
// B-frag for mfma 16x16x32: lane l holds B[k=(l>>4)*8+j][n=l&15].
// ---------------------------------------------------------------------------

// Offset conv as MFMA: out[oc<18][pix] = sum_{c,tap} W col. Block = 64 pix,
// 4 waves: wave stages c-strip [16w,+16); MFMA: mf = w>>1 (oc rows),
// p-half = w&1 (pixel halves).
__global__ __launch_bounds__(256, 2) void offset_mfma(
        const _Float16* __restrict__ xpad, const _Float16* __restrict__ wof,
        const float* __restrict__ b_off, float* __restrict__ off) {
    const int lane = threadIdx.x & 63;
    const int wid = __builtin_amdgcn_readfirstlane(threadIdx.x >> 6);
    const int bid = blockIdx.x;
    const int tile = (bid & 7) * 72 + (bid >> 3);       // XCD swizzle (576=8*72)
    const int flat = tile * 64 + lane;
    const int b_u = __builtin_amdgcn_readfirstlane(flat / HW);
    const int loc = flat - b_u * HW;
    const int h = loc / W, w = loc % W;

    __shared__ _Float16 sb[2][64 * 64];

    const _Float16* xq = xpad + (size_t)(b_u * C + wid * 16) * HPWP
                         + (h + PAD - 1) * WP + (w + PAD - 1);
    const _Float16* wbase = wof + (size_t)(wid >> 1) * 9216 + lane * 8;
    const int ph = (wid & 1) * 2;
    const int rb = lane & 15, sg = lane >> 4, sx = lane & 7;

    f32x4 acc0 = {0.f, 0.f, 0.f, 0.f}, acc1 = {0.f, 0.f, 0.f, 0.f};
    _Float16 g[16];
    half8 wc0, wc1, wn0, wn1;

    auto stage_write = [&](int kbuf) {
        #pragma unroll
        for (int u = 0; u < 2; ++u) {
            half8 hv;
            #pragma unroll
            for (int e = 0; e < 8; ++e) hv[e] = g[u * 8 + e];
            *(half8*)&sb[kbuf][lane * 64 + (((2 * wid + u) ^ sx) * 8)] = hv;
        }
    };
    auto do_mfma = [&](int kbuf) {
        #pragma unroll
        for (int p2 = 0; p2 < 2; ++p2) {
            const int row = (ph + p2) * 16 + rb;
            half8 b0 = *(const half8*)&sb[kbuf][row * 64 + ((sg ^ sx) * 8)];
            half8 b1 = *(const half8*)&sb[kbuf][row * 64 + (((4 + sg) ^ sx) * 8)];
            if (p2 == 0) {
                acc0 = __builtin_amdgcn_mfma_f32_16x16x32_f16(wc0, b0, acc0, 0, 0, 0);
                acc0 = __builtin_amdgcn_mfma_f32_16x16x32_f16(wc1, b1, acc0, 0, 0, 0);
            } else {
                acc1 = __builtin_amdgcn_mfma_f32_16x16x32_f16(wc0, b0, acc1, 0, 0, 0);
                acc1 = __builtin_amdgcn_mfma_f32_16x16x32_f16(wc1, b1, acc1, 0, 0, 0);
            }
        }
    };

    {   // tap 0
        const _Float16* xc = xq;
        #pragma unroll
        for (int j = 0; j < 16; ++j) { g[j] = xc[0]; xc += HPWP; }
        wc0 = *(const half8*)(wbase);
        wc1 = *(const half8*)(wbase + 512);
    }
    stage_write(0);
    __syncthreads();

    int kb = 0;
    for (int k = 1; k <= 8; ++k) {
        const int ky = k / 3, kx = k % 3;
        {   // issue tap-k loads + weights (consumed after MFMA below)
            const _Float16* xc = xq + ky * WP + kx;
            #pragma unroll
            for (int j = 0; j < 16; ++j) { g[j] = xc[0]; xc += HPWP; }
            const _Float16* wp = wbase + k * 1024;
            wn0 = *(const half8*)(wp);
            wn1 = *(const half8*)(wp + 512);
        }
        __builtin_amdgcn_sched_barrier(0);
        do_mfma(kb);                         // tap k-1, covers the loads above
        __builtin_amdgcn_sched_barrier(0);
        kb ^= 1;
        stage_write(kb);
        __syncthreads();
        wc0 = wn0; wc1 = wn1;
    }
    do_mfma(kb);                             // tap 8

    #pragma unroll
    for (int p2 = 0; p2 < 2; ++p2) {
        #pragma unroll
        for (int r = 0; r < 4; ++r) {
            int oc = (wid >> 1) * 16 + sg * 4 + r;
            if (oc < OFFC) {
                int n = tile * 64 + (ph + p2) * 16 + rb - b_u * HW;
                float v = (p2 == 0 ? acc0[r] : acc1[r]) + b_off[oc];
                off[((size_t)b_u * OFFC + oc) * HW + n] = v;
            }
        }
    }
}

// Deformable conv as MFMA: wave w owns o-strip [16w,+16) over all 64 pixels.
__global__ __launch_bounds__(256, 2) void deform_mfma(
        const _Float16* __restrict__ xpad, const float* __restrict__ off,
        const _Float16* __restrict__ wdf, const float* __restrict__ b_dc,
        float* __restrict__ out) {
    const int lane = threadIdx.x & 63;
    const int wid = __builtin_amdgcn_readfirstlane(threadIdx.x >> 6);
    const int bid = blockIdx.x;
    const int tile = (bid & 7) * 72 + (bid >> 3);
    const int flat = tile * 64 + lane;
    const int b_u = __builtin_amdgcn_readfirstlane(flat / HW);
    const int loc = flat - b_u * HW;
    const int h = loc / W, w = loc % W;

    __shared__ _Float16 sb[2][64 * 64];

    const _Float16* xq = xpad + (size_t)(b_u * C + wid * 16) * HPWP;
    const _Float16* wbase = wdf + (size_t)wid * 9216 + lane * 8;
    const float* offp = off + (size_t)b_u * OFFC * HW + loc;
    const int rb = lane & 15, sg = lane >> 4, sx = lane & 7;

    f32x4 acc[4] = {{0.f,0.f,0.f,0.f},{0.f,0.f,0.f,0.f},{0.f,0.f,0.f,0.f},{0.f,0.f,0.f,0.f}};
    _Float16 g00[16], g01[16], g10[16], g11[16];
    _Float16 h00, h01, h10, h11;
    half8 wc0, wc1, wn0, wn1;

    auto gather = [&](int ky, int kx, float dy, float dx) {
        float py = (float)(h + ky - 1) + dy;
        float px = (float)(w + kx - 1) + dx;
        float y0f = floorf(py), x0f = floorf(px);
        float ly = py - y0f, lx = px - x0f;
        int y0 = (int)y0f, x0 = (int)x0f;
        y0 = min(max(y0, -PAD), H + PAD - 2);   // clamp lands in zero halo
        x0 = min(max(x0, -PAD), W + PAD - 2);
        int base = (y0 + PAD) * WP + (x0 + PAD);
        float a11 = ly * lx;
        h11 = (_Float16)a11;
        h10 = (_Float16)(ly - a11);
        h01 = (_Float16)(lx - a11);
        h00 = (_Float16)(1.f - ly - lx + a11);
        const _Float16* xc = xq + base;
        #pragma unroll
        for (int j = 0; j < 16; ++j) {          // 64 independent f16 gathers
            g00[j] = xc[0]; g01[j] = xc[1]; g10[j] = xc[WP]; g11[j] = xc[WP + 1];
            xc += HPWP;
        }
    };
    auto combine_write = [&](int kbuf) {        // bilinear in f16 (err ~1e-3 abs)
        #pragma unroll
        for (int u = 0; u < 2; ++u) {
            half8 hv;
            #pragma unroll
            for (int e = 0; e < 8; ++e) {
                int j = u * 8 + e;
                hv[e] = g00[j] * h00 + g01[j] * h01 + g10[j] * h10 + g11[j] * h11;
            }
            *(half8*)&sb[kbuf][lane * 64 + (((2 * wid + u) ^ sx) * 8)] = hv;
        }
    };
    auto do_mfma = [&](int kbuf) {
        #pragma unroll
        for (int p = 0; p < 4; ++p) {
            const int row = p * 16 + rb;
            half8 b0 = *(const half8*)&sb[kbuf][row * 64 + ((sg ^ sx) * 8)];
            half8 b1 = *(const half8*)&sb[kbuf][row * 64 + (((4 + sg) ^ sx) * 8)];
            acc[p] = __builtin_amdgcn_mfma_f32_16x16x32_f16(wc0, b0, acc[p], 0, 0, 0);
            acc[p] = __builtin_amdgcn_mfma_f32_16x16x32_f16(wc1, b1, acc[p], 0, 0, 0);
        }
    };

    float dyc = offp[0], dxc = offp[HW];
    float dyn, dxn;
    gather(0, 0, dyc, dxc);
    wc0 = *(const half8*)(wbase);
    wc1 = *(const half8*)(wbase + 512);
    dyn = offp[2 * HW]; dxn = offp[3 * HW];
    combine_write(0);
    __syncthreads();

    int kb = 0;
    for (int k = 1; k <= 8; ++k) {
        const int ky = k / 3, kx = k % 3;
        gather(ky, kx, dyn, dxn);               // issue tap-k gathers
        if (k < 8) { dyn = offp[(2 * k + 2) * HW]; dxn = offp[(2 * k + 3) * HW]; }
        {
            const _Float16* wp = wbase + k * 1024;
            wn0 = *(const half8*)(wp);
            wn1 = *(const half8*)(wp + 512);
        }
        __builtin_amdgcn_sched_barrier(0);      // loads may not sink past here
        do_mfma(kb);                            // tap k-1: latency cover
        __builtin_amdgcn_sched_barrier(0);
        kb ^= 1;
        combine_write(kb);                      // waits tap-k gathers here
        __syncthreads();
        wc0 = wn0; wc1 = wn1;
    }
    do_mfma(kb);                                // tap 8

    float bias[4];
    #pragma unroll
    for (int r = 0; r < 4; ++r) bias[r] = b_dc[wid * 16 + sg * 4 + r];
    #pragma unroll
    for (int p = 0; p < 4; ++p) {
        int n = tile * 64 + p * 16 + rb - b_u * HW;
        #pragma unroll
        for (int r = 0; r < 4; ++r) {
            int o = wid * 16 + sg * 4 + r;
            out[((size_t)b_u * C + o) * HW + n] = acc[p][r] + bias[r];
        }
    }
}

// ---------------------------------------------------------------------------
extern "C" void kernel_launch(void* const* d_in, const int* in_sizes, int n_in,
                              void* d_out, int out_size, void* d_ws, size_t ws_size,
                              hipStream_t stream) {
    const float* x     = (const float*)d_in[0];
    const float* w_off = (const float*)d_in[1];
    const float* b_off = (const float*)d_in[2];
    const float* w_dc  = (const float*)d_in[3];
    const float* b_dc  = (const float*)d_in[4];
    float* out = (float*)d_out;

    char* ws = (char*)d_ws;
    float*     off  = (float*)ws;                          // 663552 f = 2654208 B
    _Float16*  xpad = (_Float16*)(ws + 2654208);           // 2768896 h = 5537792 B
    _Float16*  wdf  = (_Float16*)(ws + 2654208 + 5537792); // 36864 h
    _Float16*  wof  = (_Float16*)(ws + 2654208 + 5537792 + 73728);  // 18432 h

    prep<<<B * C * HPWP / 256, 256, 0, stream>>>(x, w_off, w_dc, xpad, wdf, wof);
    offset_mfma<<<NTILE, 256, 0, stream>>>(xpad, wof, b_off, off);
    deform_mfma<<<NTILE, 256, 0, stream>>>(xpad, off, wdf, b_dc, out);
}

// Round 8
// 36.824 us; speedup vs baseline: 12.1418x; 1.5186x over previous
//
#include <hip/hip_runtime.h>
#include <math.h>

typedef _Float16 h2    __attribute__((ext_vector_type(2)));
typedef _Float16 half8 __attribute__((ext_vector_type(8)));
typedef float    f32x4 __attribute__((ext_vector_type(4)));

constexpr int B = 4, C = 64, H = 96, W = 96;
constexpr int CP = C / 2;                   // channel pairs
constexpr int KT = 9, OFFC = 18;
constexpr int HW = H * W;
constexpr int PAD = 4;                      // zero halo; offsets are small (|off|<~0.5)
constexpr int HP = H + 2 * PAD, WP = W + 2 * PAD;   // 104 x 104
constexpr int HPWP = HP * WP;
constexpr int NTILE = B * HW / 64;          // 576 tiles of 64 pixels
constexpr int WDF_HALFS = 4 * KT * 2 * 64 * 8;   // 36864  (wave,tap,ks,lane,j)
constexpr int WOF_HALFS = 2 * KT * 2 * 64 * 8;   // 18432  (mfrag,tap,ks,lane,j)

// ---------------------------------------------------------------------------
// Prep: channel-pair-interleaved f16 zero-halo pad of x + MFMA A-frag weights.
//  xpad2[b][cp][y][x] = {x[b][2cp][y][x], x[b][2cp+1][y][x]}  (one dword gather
//  in the conv kernels fetches a bilinear corner for TWO channels)
//  wdf[wave][tap][ks][lane][j] = f16( w_dc[o=wave*16+(l&15)][c=ks*32+(l>>4)*8+j][tap] )
//  wof[mf  ][tap][ks][lane][j] = f16( w_off[oc=...][c=...][tap] ), 0 for oc>=18
// ---------------------------------------------------------------------------
__global__ __launch_bounds__(256) void prep(
        const float* __restrict__ x, const float* __restrict__ w_off,
        const float* __restrict__ w_dc,
        h2* __restrict__ xpad2, _Float16* __restrict__ wdf,
        _Float16* __restrict__ wof) {
    const int i = blockIdx.x * 256 + threadIdx.x;   // grid covers B*CP*HPWP exactly
    {   // pad (pair-interleaved)
        int col = i % WP; int t = i / WP; int row = t % HP; int bcp = t / HP;
        int b = bcp / CP, cp = bcp % CP;
        int h = row - PAD, w = col - PAD;
        h2 v; v[0] = (_Float16)0.f; v[1] = (_Float16)0.f;
        if (h >= 0 && h < H && w >= 0 && w < W) {
            const float* xp = x + ((size_t)b * C + 2 * cp) * HW + h * W + w;
            v[0] = (_Float16)xp[0];
            v[1] = (_Float16)xp[HW];
        }
        xpad2[i] = v;
    }
    if (i < WDF_HALFS) {
        int wave = i / 9216, r = i % 9216;
        int tap = r / 1024, l = (r >> 3) & 63, j = i & 7;
        int ks = (r >> 9) & 1;
        int o = wave * 16 + (l & 15);
        int c = ks * 32 + ((l >> 4) << 3) + j;
        wdf[i] = (_Float16)w_dc[((size_t)o * C + c) * KT + tap];
    }
    if (i < WOF_HALFS) {
        int mf = i / 9216, r = i % 9216;
        int tap = r / 1024, l = (r >> 3) & 63, j = i & 7;
        int ks = (r >> 9) & 1;
        int oc = mf * 16 + (l & 15);
        int c = ks * 32 + ((l >> 4) << 3) + j;
        wof[i] = (oc < OFFC) ? (_Float16)w_off[((size_t)oc * C + c) * KT + tap]
                             : (_Float16)0.f;
    }
}

// ---------------------------------------------------------------------------
// Fused offset-conv + deformable-conv. Block = 64 pixels, 4 waves.
// Phase A: offset conv via MFMA -> offt[18][64] in LDS (no global roundtrip).
// Phase B: deformable conv via MFMA, offsets read from LDS.
// LDS S-matrix: rows = pixel, 64 ch f16, 16B-slot XOR swizzle slot^=(row&7)
// (conflict-free b128 write/read; layout verified in round 7).
// ---------------------------------------------------------------------------
__global__ __launch_bounds__(256, 3) void fused_dcn(
        const h2* __restrict__ xpad2, const _Float16* __restrict__ wdf,
        const _Float16* __restrict__ wof, const float* __restrict__ b_off,
        const float* __restrict__ b_dc, float* __restrict__ out) {
    const int lane = threadIdx.x & 63;
    const int wid = __builtin_amdgcn_readfirstlane(threadIdx.x >> 6);
    const int bid = blockIdx.x;
    const int tile = (bid & 7) * 72 + (bid >> 3);       // XCD swizzle (576=8*72)
    const int flat = tile * 64 + lane;
    const int b_u = __builtin_amdgcn_readfirstlane(flat / HW);
    const int loc = flat - b_u * HW;
    const int h = loc / W, w = loc % W;
    const int rb = lane & 15, sg = lane >> 4, sx = lane & 7;

    __shared__ _Float16 sb[2][64 * 64];   // 16 KB double-buffered S
    __shared__ float offt[OFFC][64];      // 4.5 KB per-tile offsets

    // ---------------- Phase A: offset conv ----------------
    {
        const h2* xq = xpad2 + (size_t)(b_u * CP + wid * 8) * HPWP
                       + (h + PAD - 1) * WP + (w + PAD - 1);
        const _Float16* wbase = wof + (size_t)(wid >> 1) * 9216 + lane * 8;
        const int ph = (wid & 1) * 2;
        f32x4 acc0 = {0.f, 0.f, 0.f, 0.f}, acc1 = {0.f, 0.f, 0.f, 0.f};
        h2 gp[8];
        half8 wc0, wc1, wn0, wn1;

        auto stage_write = [&](int kbuf) {
            #pragma unroll
            for (int u = 0; u < 2; ++u) {
                half8 hv;
                #pragma unroll
                for (int e = 0; e < 4; ++e) {
                    hv[2 * e]     = gp[u * 4 + e][0];
                    hv[2 * e + 1] = gp[u * 4 + e][1];
                }
                *(half8*)&sb[kbuf][lane * 64 + (((2 * wid + u) ^ sx) * 8)] = hv;
            }
        };
        auto do_mfma = [&](int kbuf) {
            #pragma unroll
            for (int p2 = 0; p2 < 2; ++p2) {
                const int row = (ph + p2) * 16 + rb;
                half8 b0 = *(const half8*)&sb[kbuf][row * 64 + ((sg ^ sx) * 8)];
                half8 b1 = *(const half8*)&sb[kbuf][row * 64 + (((4 + sg) ^ sx) * 8)];
                if (p2 == 0) {
                    acc0 = __builtin_amdgcn_mfma_f32_16x16x32_f16(wc0, b0, acc0, 0, 0, 0);
                    acc0 = __builtin_amdgcn_mfma_f32_16x16x32_f16(wc1, b1, acc0, 0, 0, 0);
                } else {
                    acc1 = __builtin_amdgcn_mfma_f32_16x16x32_f16(wc0, b0, acc1, 0, 0, 0);
                    acc1 = __builtin_amdgcn_mfma_f32_16x16x32_f16(wc1, b1, acc1, 0, 0, 0);
                }
            }
        };

        {   // tap 0
            const h2* xc = xq;
            #pragma unroll
            for (int j = 0; j < 8; ++j) { gp[j] = xc[0]; xc += HPWP; }
            wc0 = *(const half8*)(wbase);
            wc1 = *(const half8*)(wbase + 512);
        }
        stage_write(0);
        __syncthreads();

        int kb = 0;
        for (int k = 1; k <= 8; ++k) {
            const int ky = k / 3, kx = k % 3;
            {
                const h2* xc = xq + ky * WP + kx;
                #pragma unroll
                for (int j = 0; j < 8; ++j) { gp[j] = xc[0]; xc += HPWP; }
                const _Float16* wp = wbase + k * 1024;
                wn0 = *(const half8*)(wp);
                wn1 = *(const half8*)(wp + 512);
            }
            __builtin_amdgcn_sched_barrier(0);
            do_mfma(kb);                     // tap k-1 covers the loads above
            __builtin_amdgcn_sched_barrier(0);
            kb ^= 1;
            stage_write(kb);
            __syncthreads();
            wc0 = wn0; wc1 = wn1;
        }
        do_mfma(kb);                         // tap 8

        #pragma unroll
        for (int p2 = 0; p2 < 2; ++p2) {
            #pragma unroll
            for (int r = 0; r < 4; ++r) {
                int oc = (wid >> 1) * 16 + sg * 4 + r;
                if (oc < OFFC)
                    offt[oc][(ph + p2) * 16 + rb] =
                        (p2 == 0 ? acc0[r] : acc1[r]) + b_off[oc];
            }
        }
    }
    __syncthreads();

    // ---------------- Phase B: deformable conv ----------------
    {
        const h2* xq = xpad2 + (size_t)(b_u * CP + wid * 8) * HPWP;
        const _Float16* wbase = wdf + (size_t)wid * 9216 + lane * 8;
        f32x4 acc[4] = {{0.f,0.f,0.f,0.f},{0.f,0.f,0.f,0.f},
                        {0.f,0.f,0.f,0.f},{0.f,0.f,0.f,0.f}};
        h2 v00[8], v01[8], v10[8], v11[8];
        h2 W00, W01, W10, W11;
        half8 wc0, wc1, wn0, wn1;

        auto gather = [&](int ky, int kx, float dy, float dx) {
            float py = (float)(h + ky - 1) + dy;
            float px = (float)(w + kx - 1) + dx;
            float y0f = floorf(py), x0f = floorf(px);
            float ly = py - y0f, lx = px - x0f;
            int y0 = (int)y0f, x0 = (int)x0f;
            y0 = min(max(y0, -PAD), H + PAD - 2);   // clamp lands in zero halo
            x0 = min(max(x0, -PAD), W + PAD - 2);
            int base = (y0 + PAD) * WP + (x0 + PAD);
            float a11 = ly * lx;
            _Float16 f11 = (_Float16)a11;
            _Float16 f10 = (_Float16)(ly - a11);
            _Float16 f01 = (_Float16)(lx - a11);
            _Float16 f00 = (_Float16)(1.f - ly - lx + a11);
            W00[0] = f00; W00[1] = f00;
            W01[0] = f01; W01[1] = f01;
            W10[0] = f10; W10[1] = f10;
            W11[0] = f11; W11[1] = f11;
            const h2* xc = xq + base;
            #pragma unroll
            for (int j = 0; j < 8; ++j) {   // 32 dword gathers (2 ch each)
                v00[j] = xc[0]; v01[j] = xc[1];
                v10[j] = xc[WP]; v11[j] = xc[WP + 1];
                xc += HPWP;
            }
        };
        auto combine_write = [&](int kbuf) {    // packed f16 bilinear
            #pragma unroll
            for (int u = 0; u < 2; ++u) {
                half8 hv;
                #pragma unroll
                for (int e = 0; e < 4; ++e) {
                    int j = u * 4 + e;
                    h2 s = v00[j] * W00 + v01[j] * W01 + v10[j] * W10 + v11[j] * W11;
                    hv[2 * e]     = s[0];
                    hv[2 * e + 1] = s[1];
                }
                *(half8*)&sb[kbuf][lane * 64 + (((2 * wid + u) ^ sx) * 8)] = hv;
            }
        };
        auto do_mfma = [&](int kbuf) {
            #pragma unroll
            for (int p = 0; p < 4; ++p) {
                const int row = p * 16 + rb;
                half8 b0 = *(const half8*)&sb[kbuf][row * 64 + ((sg ^ sx) * 8)];
                half8 b1 = *(const half8*)&sb[kbuf][row * 64 + (((4 + sg) ^ sx) * 8)];
                acc[p] = __builtin_amdgcn_mfma_f32_16x16x32_f16(wc0, b0, acc[p], 0, 0, 0);
                acc[p] = __builtin_amdgcn_mfma_f32_16x16x32_f16(wc1, b1, acc[p], 0, 0, 0);
            }
        };

        float dyn = offt[0][lane], dxn = offt[1][lane];
        gather(0, 0, dyn, dxn);
        wc0 = *(const half8*)(wbase);
        wc1 = *(const half8*)(wbase + 512);
        dyn = offt[2][lane]; dxn = offt[3][lane];
        combine_write(0);
        __syncthreads();

        int kb = 0;
        for (int k = 1; k <= 8; ++k) {
            const int ky = k / 3, kx = k % 3;
            gather(ky, kx, dyn, dxn);           // issue tap-k gathers
            if (k < 8) { dyn = offt[2 * k + 2][lane]; dxn = offt[2 * k + 3][lane]; }
            {
                const _Float16* wp = wbase + k * 1024;
                wn0 = *(const half8*)(wp);
                wn1 = *(const half8*)(wp + 512);
            }
            __builtin_amdgcn_sched_barrier(0);  // loads may not sink past here
            do_mfma(kb);                        // tap k-1: latency cover
            __builtin_amdgcn_sched_barrier(0);
            kb ^= 1;
            combine_write(kb);                  // waits tap-k gathers here
            __syncthreads();
            wc0 = wn0; wc1 = wn1;
        }
        do_mfma(kb);                            // tap 8

        #pragma unroll
        for (int p = 0; p < 4; ++p) {
            int n = tile * 64 + p * 16 + rb - b_u * HW;
            #pragma unroll
            for (int r = 0; r < 4; ++r) {
                int o = wid * 16 + sg * 4 + r;
                out[((size_t)b_u * C + o) * HW + n] = acc[p][r] + b_dc[o];
            }
        }
    }
}

// ---------------------------------------------------------------------------
extern "C" void kernel_launch(void* const* d_in, const int* in_sizes, int n_in,
                              void* d_out, int out_size, void* d_ws, size_t ws_size,
                              hipStream_t stream) {
    const float* x     = (const float*)d_in[0];
    const float* w_off = (const float*)d_in[1];
    const float* b_off = (const float*)d_in[2];
    const float* w_dc  = (const float*)d_in[3];
    const float* b_dc  = (const float*)d_in[4];
    float* out = (float*)d_out;

    char* ws = (char*)d_ws;
    h2*        xpad2 = (h2*)ws;                            // 1384448 h2 = 5537792 B
    _Float16*  wdf   = (_Float16*)(ws + 5537792);          // 36864 h
    _Float16*  wof   = (_Float16*)(ws + 5537792 + 73728);  // 18432 h

    prep<<<B * CP * HPWP / 256, 256, 0, stream>>>(x, w_off, w_dc, xpad2, wdf, wof);
    fused_dcn<<<NTILE, 256, 0, stream>>>(xpad2, wdf, wof, b_off, b_dc, out);
}

// Round 9
// 34.721 us; speedup vs baseline: 12.8773x; 1.0606x over previous
//
#include <hip/hip_runtime.h>
#include <math.h>

typedef _Float16 h2    __attribute__((ext_vector_type(2)));
typedef _Float16 h4    __attribute__((ext_vector_type(4)));
typedef _Float16 half8 __attribute__((ext_vector_type(8)));
typedef float    f32x4 __attribute__((ext_vector_type(4)));

constexpr int B = 4, C = 64, H = 96, W = 96;
constexpr int CP = C / 2;                   // channel pairs
constexpr int KT = 9, OFFC = 18;
constexpr int HW = H * W;
constexpr int PAD = 4;                      // zero halo
constexpr int HP = H + 2 * PAD, WP = W + 2 * PAD;   // 104 x 104
constexpr int HPWP = HP * WP;
constexpr int NT32 = B * HW / 32;           // 1152 tiles of 32 pixels
constexpr int WDF_HALFS = 4 * KT * 2 * 64 * 8;   // 36864
constexpr int WOF_HALFS = 2 * KT * 2 * 64 * 8;   // 18432

// ---------------------------------------------------------------------------
// Prep: channel-pair-interleaved f16 zero-halo pad + MFMA A-frag weights
// (identical to round 8; layouts verified).
// ---------------------------------------------------------------------------
__global__ __launch_bounds__(256) void prep(
        const float* __restrict__ x, const float* __restrict__ w_off,
        const float* __restrict__ w_dc,
        h2* __restrict__ xpad2, _Float16* __restrict__ wdf,
        _Float16* __restrict__ wof) {
    const int i = blockIdx.x * 256 + threadIdx.x;   // grid covers B*CP*HPWP exactly
    {
        int col = i % WP; int t = i / WP; int row = t % HP; int bcp = t / HP;
        int b = bcp / CP, cp = bcp % CP;
        int h = row - PAD, w = col - PAD;
        h2 v; v[0] = (_Float16)0.f; v[1] = (_Float16)0.f;
        if (h >= 0 && h < H && w >= 0 && w < W) {
            const float* xp = x + ((size_t)b * C + 2 * cp) * HW + h * W + w;
            v[0] = (_Float16)xp[0];
            v[1] = (_Float16)xp[HW];
        }
        xpad2[i] = v;
    }
    if (i < WDF_HALFS) {
        int wave = i / 9216, r = i % 9216;
        int tap = r / 1024, l = (r >> 3) & 63, j = i & 7;
        int ks = (r >> 9) & 1;
        int o = wave * 16 + (l & 15);
        int c = ks * 32 + ((l >> 4) << 3) + j;
        wdf[i] = (_Float16)w_dc[((size_t)o * C + c) * KT + tap];
    }
    if (i < WOF_HALFS) {
        int mf = i / 9216, r = i % 9216;
        int tap = r / 1024, l = (r >> 3) & 63, j = i & 7;
        int ks = (r >> 9) & 1;
        int oc = mf * 16 + (l & 15);
        int c = ks * 32 + ((l >> 4) << 3) + j;
        wof[i] = (oc < OFFC) ? (_Float16)w_off[((size_t)oc * C + c) * KT + tap]
                             : (_Float16)0.f;
    }
}

// ---------------------------------------------------------------------------
// Fused DCN, 32-pixel tiles, 2-deep gather pipeline.
// Block = 4 waves. lane&31 = pixel, lane>>5 = cp-half. Wave w stages
// cp strip [8w,8w+8); S = [32 pix][64 ch f16] XOR-swizzled (slot^=row&7).
// Phase A: offset conv -> offt[18][32] LDS. Phase B: deform conv -> out.
// ---------------------------------------------------------------------------
__global__ __launch_bounds__(256, 4) void fused_dcn32(
        const h2* __restrict__ xpad2, const _Float16* __restrict__ wdf,
        const _Float16* __restrict__ wof, const float* __restrict__ b_off,
        const float* __restrict__ b_dc, float* __restrict__ out) {
    const int lane = threadIdx.x & 63;
    const int wid = __builtin_amdgcn_readfirstlane(threadIdx.x >> 6);
    const int l31 = lane & 31, lh = lane >> 5;
    const int bid = blockIdx.x;
    const int tile = (bid & 7) * 144 + (bid >> 3);      // XCD swizzle (1152=8*144)
    const int flat = tile * 32 + l31;
    const int b_u = __builtin_amdgcn_readfirstlane(flat / HW);
    const int loc = flat - b_u * HW;
    const int h = loc / W, w = loc % W;
    const int rb = lane & 15, sg = lane >> 4;

    __shared__ _Float16 sb[2][32 * 64];   // 8 KB double-buffered S
    __shared__ float offt[OFFC][32];      // per-tile offsets

    const int cpb = wid * 8 + lh * 4;                   // my 4 channel-pairs
    const h2* xq = xpad2 + (size_t)(b_u * CP + cpb) * HPWP;
    const int slot = 2 * wid + lh;                      // my 16B S-slot

    // ---------------- Phase A: offset conv ----------------
    {
        const h2* xwin = xq + (h + PAD - 1) * WP + (w + PAD - 1);
        const _Float16* wbase = wof + (size_t)(wid >> 1) * 9216 + lane * 8;
        const int ph = wid & 1;
        f32x4 acc = {0.f, 0.f, 0.f, 0.f};
        h2 gA[2][4];
        half8 wc0, wc1, wn0, wn1;

        auto loadwin = [&](int s, int k) {
            const h2* xc = xwin + (k / 3) * WP + (k % 3);
            #pragma unroll
            for (int j = 0; j < 4; ++j) { gA[s][j] = xc[0]; xc += HPWP; }
        };
        auto stage = [&](int kbuf, int s) {
            half8 hv;
            #pragma unroll
            for (int e = 0; e < 4; ++e) { hv[2*e] = gA[s][e][0]; hv[2*e+1] = gA[s][e][1]; }
            *(half8*)&sb[kbuf][l31 * 64 + ((slot ^ (l31 & 7)) * 8)] = hv;
        };
        auto mfmaA = [&](int kbuf) {
            const int row = ph * 16 + rb;
            half8 b0 = *(const half8*)&sb[kbuf][row * 64 + ((sg ^ (row & 7)) * 8)];
            half8 b1 = *(const half8*)&sb[kbuf][row * 64 + (((4 + sg) ^ (row & 7)) * 8)];
            acc = __builtin_amdgcn_mfma_f32_16x16x32_f16(wc0, b0, acc, 0, 0, 0);
            acc = __builtin_amdgcn_mfma_f32_16x16x32_f16(wc1, b1, acc, 0, 0, 0);
        };

        loadwin(0, 0); loadwin(1, 1);
        wc0 = *(const half8*)(wbase);
        wc1 = *(const half8*)(wbase + 512);
        stage(0, 0);
        __syncthreads();
        #pragma unroll
        for (int k = 1; k <= 8; ++k) {
            if (k < 8) loadwin((k + 1) & 1, k + 1);
            const _Float16* wp = wbase + k * 1024;
            wn0 = *(const half8*)(wp);
            wn1 = *(const half8*)(wp + 512);
            __builtin_amdgcn_sched_barrier(0);
            mfmaA((k - 1) & 1);
            __builtin_amdgcn_sched_barrier(0);
            stage(k & 1, k & 1);
            __syncthreads();
            wc0 = wn0; wc1 = wn1;
        }
        mfmaA(0);                                 // tap 8

        #pragma unroll
        for (int r = 0; r < 4; ++r) {
            int oc = (wid >> 1) * 16 + sg * 4 + r;
            if (oc < OFFC) offt[oc][ph * 16 + rb] = acc[r] + b_off[oc];
        }
    }
    __syncthreads();

    // ---------------- Phase B: deformable conv ----------------
    {
        const _Float16* wbase = wdf + (size_t)wid * 9216 + lane * 8;
        f32x4 acc[2] = {{0.f,0.f,0.f,0.f}, {0.f,0.f,0.f,0.f}};
        h4 vA[2][4], vB[2][4];               // [set][cp]; (x0,x0+1) pair loads
        h2 W00[2], W01[2], W10[2], W11[2];
        half8 wc0, wc1, wn0, wn1;

        auto gather = [&](int s, int k) {
            float dy = offt[2 * k][l31], dx = offt[2 * k + 1][l31];
            float py = (float)(h + k / 3 - 1) + dy;
            float px = (float)(w + k % 3 - 1) + dx;
            float y0f = floorf(py), x0f = floorf(px);
            float ly = py - y0f, lx = px - x0f;
            int y0 = (int)y0f, x0 = (int)x0f;
            y0 = min(max(y0, -PAD), H + PAD - 2);
            x0 = min(max(x0, -PAD), W + PAD - 2);
            int base = (y0 + PAD) * WP + (x0 + PAD);
            float a11 = ly * lx;
            _Float16 f11 = (_Float16)a11;
            _Float16 f10 = (_Float16)(ly - a11);
            _Float16 f01 = (_Float16)(lx - a11);
            _Float16 f00 = (_Float16)(1.f - ly - lx + a11);
            W00[s][0] = f00; W00[s][1] = f00;
            W01[s][0] = f01; W01[s][1] = f01;
            W10[s][0] = f10; W10[s][1] = f10;
            W11[s][0] = f11; W11[s][1] = f11;
            const h2* xc = xq + base;
            #pragma unroll
            for (int j = 0; j < 4; ++j) {    // 8 x 8B loads (2 corners x 2 ch)
                __builtin_memcpy(&vA[s][j], xc, 8);
                __builtin_memcpy(&vB[s][j], xc + WP, 8);
                xc += HPWP;
            }
        };
        auto combine = [&](int kbuf, int s) {
            half8 hv;
            #pragma unroll
            for (int j = 0; j < 4; ++j) {
                h2 c00; c00[0] = vA[s][j][0]; c00[1] = vA[s][j][1];
                h2 c01; c01[0] = vA[s][j][2]; c01[1] = vA[s][j][3];
                h2 c10; c10[0] = vB[s][j][0]; c10[1] = vB[s][j][1];
                h2 c11; c11[0] = vB[s][j][2]; c11[1] = vB[s][j][3];
                h2 sres = c00 * W00[s] + c01 * W01[s] + c10 * W10[s] + c11 * W11[s];
                hv[2 * j] = sres[0]; hv[2 * j + 1] = sres[1];
            }
            *(half8*)&sb[kbuf][l31 * 64 + ((slot ^ (l31 & 7)) * 8)] = hv;
        };
        auto mfmaB = [&](int kbuf) {
            #pragma unroll
            for (int p = 0; p < 2; ++p) {
                const int row = p * 16 + rb;
                half8 b0 = *(const half8*)&sb[kbuf][row * 64 + ((sg ^ (row & 7)) * 8)];
                half8 b1 = *(const half8*)&sb[kbuf][row * 64 + (((4 + sg) ^ (row & 7)) * 8)];
                acc[p] = __builtin_amdgcn_mfma_f32_16x16x32_f16(wc0, b0, acc[p], 0, 0, 0);
                acc[p] = __builtin_amdgcn_mfma_f32_16x16x32_f16(wc1, b1, acc[p], 0, 0, 0);
            }
        };

        gather(0, 0); gather(1, 1);          // 2-deep prologue
        wc0 = *(const half8*)(wbase);
        wc1 = *(const half8*)(wbase + 512);
        combine(0, 0);
        __syncthreads();
        #pragma unroll
        for (int k = 1; k <= 8; ++k) {
            if (k < 8) gather((k + 1) & 1, k + 1);   // issued a full tap early
            const _Float16* wp = wbase + k * 1024;
            wn0 = *(const half8*)(wp);
            wn1 = *(const half8*)(wp + 512);
            __builtin_amdgcn_sched_barrier(0);
            mfmaB((k - 1) & 1);
            __builtin_amdgcn_sched_barrier(0);
            combine(k & 1, k & 1);           // waits set k (issued at k-1)
            __syncthreads();
            wc0 = wn0; wc1 = wn1;
        }
        mfmaB(0);                            // tap 8

        const int loc0 = tile * 32 - b_u * HW;
        #pragma unroll
        for (int p = 0; p < 2; ++p) {
            int n = loc0 + p * 16 + rb;
            #pragma unroll
            for (int r = 0; r < 4; ++r) {
                int o = wid * 16 + sg * 4 + r;
                out[((size_t)b_u * C + o) * HW + n] = acc[p][r] + b_dc[o];
            }
        }
    }
}

// ---------------------------------------------------------------------------
extern "C" void kernel_launch(void* const* d_in, const int* in_sizes, int n_in,
                              void* d_out, int out_size, void* d_ws, size_t ws_size,
                              hipStream_t stream) {
    const float* x     = (const float*)d_in[0];
    const float* w_off = (const float*)d_in[1];
    const float* b_off = (const float*)d_in[2];
    const float* w_dc  = (const float*)d_in[3];
    const float* b_dc  = (const float*)d_in[4];
    float* out = (float*)d_out;

    char* ws = (char*)d_ws;
    h2*        xpad2 = (h2*)ws;                            // 5537792 B
    _Float16*  wdf   = (_Float16*)(ws + 5537792);          // 36864 h
    _Float16*  wof   = (_Float16*)(ws + 5537792 + 73728);  // 18432 h

    prep<<<B * CP * HPWP / 256, 256, 0, stream>>>(x, w_off, w_dc, xpad2, wdf, wof);
    fused_dcn32<<<NT32, 256, 0, stream>>>(xpad2, wdf, wof, b_off, b_dc, out);
}

// Round 10
// 34.644 us; speedup vs baseline: 12.9058x; 1.0022x over previous
//
#include <hip/hip_runtime.h>
#include <math.h>

typedef _Float16 h4    __attribute__((ext_vector_type(4)));
typedef _Float16 half8 __attribute__((ext_vector_type(8)));
typedef float    f32x4 __attribute__((ext_vector_type(4)));

constexpr int B = 4, C = 64, H = 96, W = 96;
constexpr int NQ = C / 4;                   // 16 channel-quads
constexpr int KT = 9, OFFC = 18;
constexpr int HW = H * W;
constexpr int PAD = 4;                      // zero halo
constexpr int HP = H + 2 * PAD, WP = W + 2 * PAD;   // 104 x 104
constexpr int HPWP = HP * WP;
constexpr int WDF_HALFS = 4 * KT * 2 * 64 * 8;   // 36864  [m][tap][ks][lane][j]
constexpr int WOF_HALFS = 2 * KT * 2 * 64 * 8;   // 18432  [mf][tap][ks][lane][j]

struct h4x2 { h4 a, b; };                   // 16B: two adjacent columns (x0, x0+1)

// ---------------------------------------------------------------------------
// Prep: quad-interleaved f16 zero-halo pad (xpad4[b][q][y][x] = 4 channels per
// 8B cell -> one 16B gather = 2 corners x 4 ch) + MFMA A-frag weights
// (wdf/wof layouts identical to rounds 7-9, verified).
// ---------------------------------------------------------------------------
__global__ __launch_bounds__(256) void prep(
        const float* __restrict__ x, const float* __restrict__ w_off,
        const float* __restrict__ w_dc,
        h4* __restrict__ xpad4, _Float16* __restrict__ wdf,
        _Float16* __restrict__ wof) {
    const int i = blockIdx.x * 256 + threadIdx.x;   // covers B*NQ*HPWP exactly
    {
        int col = i % WP; int t = i / WP; int row = t % HP; int bq = t / HP;
        int b = bq / NQ, q = bq % NQ;
        int h = row - PAD, w = col - PAD;
        h4 v; v[0] = v[1] = v[2] = v[3] = (_Float16)0.f;
        if (h >= 0 && h < H && w >= 0 && w < W) {
            const float* xp = x + ((size_t)b * C + 4 * q) * HW + h * W + w;
            v[0] = (_Float16)xp[0];
            v[1] = (_Float16)xp[HW];
            v[2] = (_Float16)xp[2 * HW];
            v[3] = (_Float16)xp[3 * HW];
        }
        xpad4[i] = v;
    }
    if (i < WDF_HALFS) {
        int m = i / 9216, r = i % 9216;
        int tap = r / 1024, l = (r >> 3) & 63, j = i & 7;
        int ks = (r >> 9) & 1;
        int o = m * 16 + (l & 15);
        int c = ks * 32 + ((l >> 4) << 3) + j;
        wdf[i] = (_Float16)w_dc[((size_t)o * C + c) * KT + tap];
    }
    if (i < WOF_HALFS) {
        int mf = i / 9216, r = i % 9216;
        int tap = r / 1024, l = (r >> 3) & 63, j = i & 7;
        int ks = (r >> 9) & 1;
        int oc = mf * 16 + (l & 15);
        int c = ks * 32 + ((l >> 4) << 3) + j;
        wof[i] = (oc < OFFC) ? (_Float16)w_off[((size_t)oc * C + c) * KT + tap]
                             : (_Float16)0.f;
    }
}

// ---------------------------------------------------------------------------
// Barrier-free fused DCN. Block = 4 INDEPENDENT waves (no __syncthreads).
// Each wave: 16 pixels (one row segment), all 64 out-ch.
// Lane l = pixel (l&15), channel-group g=(l>>4): lane gathers exactly its own
// MFMA B-fragment elements (ch 32ks+8g+j of pixel l&15) -> no cross-wave
// sample sharing, no LDS staging of samples, zero barriers.
// Phase A: offset conv (M=32 padded, wof zero rows) -> wave-private offt LDS.
// Phase B: deform conv, gathers 2-deep pipelined, weights streamed per tap.
// ---------------------------------------------------------------------------
__global__ __launch_bounds__(256, 2) void fused_wave(
        const h4* __restrict__ xpad4, const _Float16* __restrict__ wdf,
        const _Float16* __restrict__ wof, const float* __restrict__ b_off,
        const float* __restrict__ b_dc, float* __restrict__ out) {
    const int lane = threadIdx.x & 63;
    const int wid = __builtin_amdgcn_readfirstlane(threadIdx.x >> 6);
    const int p = lane & 15, g = lane >> 4;
    const int bid = blockIdx.x;
    const int tile = (bid & 7) * 72 + (bid >> 3);   // XCD swizzle (576 = 8*72)
    const int wt = tile * 4 + wid;                  // wave-tile 0..2303
    const int flat0 = wt * 16;
    const int b_u = __builtin_amdgcn_readfirstlane(flat0 / HW);
    const int loc0 = flat0 - b_u * HW;
    const int h = loc0 / W;                         // uniform per wave (16|96)
    const int w = loc0 % W + p;                     // my pixel's column

    __shared__ float offt[4][2 * KT][16];           // wave-private slabs

    const h4* xq = xpad4 + (size_t)b_u * NQ * HPWP;

    // ---------------- Phase A: offset conv ----------------
    {
        f32x4 a0 = {0.f,0.f,0.f,0.f}, a1 = {0.f,0.f,0.f,0.f};
        half8 bf[2][2];                             // [set][ks]
        const _Float16* wofb = wof + lane * 8;

        auto issueA = [&](int s, int k) {
            const int cell = (h + k / 3 - 1 + PAD) * WP + (w + k % 3 - 1 + PAD);
            #pragma unroll
            for (int ks = 0; ks < 2; ++ks) {
                h4 q0 = xq[(size_t)(ks * 8 + 2 * g)     * HPWP + cell];
                h4 q1 = xq[(size_t)(ks * 8 + 2 * g + 1) * HPWP + cell];
                bf[s][ks] = __builtin_shufflevector(q0, q1, 0,1,2,3,4,5,6,7);
            }
        };
        auto mfmaA = [&](int s, int k) {
            #pragma unroll
            for (int ks = 0; ks < 2; ++ks) {
                half8 wf0 = *(const half8*)(wofb + k * 1024 + ks * 512);
                half8 wf1 = *(const half8*)(wofb + 9216 + k * 1024 + ks * 512);
                a0 = __builtin_amdgcn_mfma_f32_16x16x32_f16(wf0, bf[s][ks], a0, 0, 0, 0);
                a1 = __builtin_amdgcn_mfma_f32_16x16x32_f16(wf1, bf[s][ks], a1, 0, 0, 0);
            }
        };

        issueA(0, 0); issueA(1, 1);
        #pragma unroll
        for (int k = 1; k <= 8; ++k) {
            __builtin_amdgcn_sched_barrier(0);
            mfmaA((k - 1) & 1, k - 1);
            __builtin_amdgcn_sched_barrier(0);
            if (k < 8) issueA((k - 1) & 1, k + 1);  // tap t lives in set t&1
        }
        mfmaA(0, 8);

        #pragma unroll
        for (int r = 0; r < 4; ++r) {               // oc 0..15
            const int oc = g * 4 + r;
            offt[wid][oc][p] = a0[r] + b_off[oc];
        }
        if (g == 0) {                               // oc 16,17
            #pragma unroll
            for (int r = 0; r < 2; ++r)
                offt[wid][16 + r][p] = a1[r] + b_off[16 + r];
        }
    }
    // no barrier: offt is wave-private; same-wave ds ordering via lgkmcnt

    // ---------------- Phase B: deformable conv ----------------
    {
        f32x4 acc[4] = {{0.f,0.f,0.f,0.f},{0.f,0.f,0.f,0.f},
                        {0.f,0.f,0.f,0.f},{0.f,0.f,0.f,0.f}};
        h4x2 rt[2][2][2], rb[2][2][2];              // [set][ks][q2] top/bottom rows
        h4 Wc[2][4];                                // [set][corner] splats
        const _Float16* wdfb = wdf + lane * 8;

        auto issueB = [&](int s, int k) {
            const float dy = offt[wid][2 * k][p];
            const float dx = offt[wid][2 * k + 1][p];
            const float py = (float)(h + k / 3 - 1) + dy;
            const float px = (float)(w + k % 3 - 1) + dx;
            const float y0f = floorf(py), x0f = floorf(px);
            const float ly = py - y0f, lx = px - x0f;
            int y0 = (int)y0f, x0 = (int)x0f;
            y0 = min(max(y0, -PAD), H + PAD - 2);   // clamp lands in zero halo
            x0 = min(max(x0, -PAD), W + PAD - 2);
            const int base = (y0 + PAD) * WP + (x0 + PAD);
            const float a11 = ly * lx;
            const _Float16 f11 = (_Float16)a11;
            const _Float16 f10 = (_Float16)(ly - a11);
            const _Float16 f01 = (_Float16)(lx - a11);
            const _Float16 f00 = (_Float16)(1.f - ly - lx + a11);
            #pragma unroll
            for (int e = 0; e < 4; ++e) { Wc[s][0][e] = f00; Wc[s][1][e] = f01;
                                          Wc[s][2][e] = f10; Wc[s][3][e] = f11; }
            #pragma unroll
            for (int ks = 0; ks < 2; ++ks) {
                #pragma unroll
                for (int q2 = 0; q2 < 2; ++q2) {
                    const h4* qp = xq + (size_t)(ks * 8 + 2 * g + q2) * HPWP + base;
                    __builtin_memcpy(&rt[s][ks][q2], qp, 16);        // (y0, x0..x0+1)
                    __builtin_memcpy(&rb[s][ks][q2], qp + WP, 16);   // (y0+1, ...)
                }
            }
        };
        auto mfmaB = [&](int s, int k) {
            half8 wf[4][2];
            #pragma unroll
            for (int m = 0; m < 4; ++m)
                #pragma unroll
                for (int ks = 0; ks < 2; ++ks)
                    wf[m][ks] = *(const half8*)(wdfb + m * 9216 + k * 1024 + ks * 512);
            #pragma unroll
            for (int ks = 0; ks < 2; ++ks) {
                h4 s0 = rt[s][ks][0].a * Wc[s][0] + rt[s][ks][0].b * Wc[s][1]
                      + rb[s][ks][0].a * Wc[s][2] + rb[s][ks][0].b * Wc[s][3];
                h4 s1 = rt[s][ks][1].a * Wc[s][0] + rt[s][ks][1].b * Wc[s][1]
                      + rb[s][ks][1].a * Wc[s][2] + rb[s][ks][1].b * Wc[s][3];
                half8 bfr = __builtin_shufflevector(s0, s1, 0,1,2,3,4,5,6,7);
                #pragma unroll
                for (int m = 0; m < 4; ++m)
                    acc[m] = __builtin_amdgcn_mfma_f32_16x16x32_f16(wf[m][ks], bfr,
                                                                    acc[m], 0, 0, 0);
            }
        };

        issueB(0, 0); issueB(1, 1);
        #pragma unroll
        for (int k = 1; k <= 8; ++k) {
            __builtin_amdgcn_sched_barrier(0);
            mfmaB((k - 1) & 1, k - 1);
            __builtin_amdgcn_sched_barrier(0);
            if (k < 8) issueB((k - 1) & 1, k + 1);
        }
        mfmaB(0, 8);

        #pragma unroll
        for (int m = 0; m < 4; ++m) {
            #pragma unroll
            for (int r = 0; r < 4; ++r) {
                const int o = m * 16 + g * 4 + r;
                out[((size_t)b_u * C + o) * HW + loc0 + p] = acc[m][r] + b_dc[o];
            }
        }
    }
}

// ---------------------------------------------------------------------------
extern "C" void kernel_launch(void* const* d_in, const int* in_sizes, int n_in,
                              void* d_out, int out_size, void* d_ws, size_t ws_size,
                              hipStream_t stream) {
    const float* x     = (const float*)d_in[0];
    const float* w_off = (const float*)d_in[1];
    const float* b_off = (const float*)d_in[2];
    const float* w_dc  = (const float*)d_in[3];
    const float* b_dc  = (const float*)d_in[4];
    float* out = (float*)d_out;

    char* ws = (char*)d_ws;
    h4*        xpad4 = (h4*)ws;                            // 692224 * 8B = 5537792 B
    _Float16*  wdf   = (_Float16*)(ws + 5537792);          // 36864 h
    _Float16*  wof   = (_Float16*)(ws + 5537792 + 73728);  // 18432 h

    prep<<<B * NQ * HPWP / 256, 256, 0, stream>>>(x, w_off, w_dc, xpad4, wdf, wof);
    fused_wave<<<576, 256, 0, stream>>>(xpad4, wdf, wof, b_off, b_dc, out);
}

// Round 11
// 30.395 us; speedup vs baseline: 14.7098x; 1.1398x over previous
//
#include <hip/hip_runtime.h>
#include <math.h>

typedef _Float16 h4    __attribute__((ext_vector_type(4)));
typedef _Float16 half8 __attribute__((ext_vector_type(8)));
typedef float    f32x4 __attribute__((ext_vector_type(4)));

constexpr int B = 4, C = 64, H = 96, W = 96;
constexpr int NQ = C / 4;                   // 16 channel-quads
constexpr int KT = 9, OFFC = 18;
constexpr int HW = H * W;
constexpr int PAD = 4;                      // zero halo
constexpr int HP = H + 2 * PAD, WP = W + 2 * PAD;   // 104 x 104
constexpr int HPWP = HP * WP;
constexpr int WDF_HALFS = 4 * KT * 2 * 64 * 8;   // 36864  [m][tap][ks][lane][j]
constexpr int WOF_HALFS = 2 * KT * 2 * 64 * 8;   // 18432  [mf][tap][ks][lane][j]

struct h4x2 { h4 a, b; };                   // 16B: two adjacent columns (x0, x0+1)

// ---------------------------------------------------------------------------
// Prep: quad-interleaved f16 zero-halo pad + MFMA A-frag weights
// (identical to round 10; layouts verified).
// ---------------------------------------------------------------------------
__global__ __launch_bounds__(256) void prep(
        const float* __restrict__ x, const float* __restrict__ w_off,
        const float* __restrict__ w_dc,
        h4* __restrict__ xpad4, _Float16* __restrict__ wdf,
        _Float16* __restrict__ wof) {
    const int i = blockIdx.x * 256 + threadIdx.x;   // covers B*NQ*HPWP exactly
    {
        int col = i % WP; int t = i / WP; int row = t % HP; int bq = t / HP;
        int b = bq / NQ, q = bq % NQ;
        int h = row - PAD, w = col - PAD;
        h4 v; v[0] = v[1] = v[2] = v[3] = (_Float16)0.f;
        if (h >= 0 && h < H && w >= 0 && w < W) {
            const float* xp = x + ((size_t)b * C + 4 * q) * HW + h * W + w;
            v[0] = (_Float16)xp[0];
            v[1] = (_Float16)xp[HW];
            v[2] = (_Float16)xp[2 * HW];
            v[3] = (_Float16)xp[3 * HW];
        }
        xpad4[i] = v;
    }
    if (i < WDF_HALFS) {
        int m = i / 9216, r = i % 9216;
        int tap = r / 1024, l = (r >> 3) & 63, j = i & 7;
        int ks = (r >> 9) & 1;
        int o = m * 16 + (l & 15);
        int c = ks * 32 + ((l >> 4) << 3) + j;
        wdf[i] = (_Float16)w_dc[((size_t)o * C + c) * KT + tap];
    }
    if (i < WOF_HALFS) {
        int mf = i / 9216, r = i % 9216;
        int tap = r / 1024, l = (r >> 3) & 63, j = i & 7;
        int ks = (r >> 9) & 1;
        int oc = mf * 16 + (l & 15);
        int c = ks * 32 + ((l >> 4) << 3) + j;
        wof[i] = (oc < OFFC) ? (_Float16)w_off[((size_t)oc * C + c) * KT + tap]
                             : (_Float16)0.f;
    }
}

// ---------------------------------------------------------------------------
// Fused DCN, wave-autonomous (round-10 structure) + LDS-resident deform
// weights. Block = 4 waves; wave = 16 pixels x all 64 out-ch; lane l =
// pixel (l&15), ch-group g=(l>>4) gathers exactly its own B-fragment.
// NEW: wdf (73.7 KB, identical across the 4 waves) is staged once into LDS
// via global_load_lds at kernel entry (covered by Phase A), so Phase B's
// per-tap weight reads are ds_read_b128 instead of ~200-cyc L2 hits.
// Phase A weights get a 1-tap-ahead register prefetch.
// ---------------------------------------------------------------------------
__global__ __launch_bounds__(256, 2) void fused_wave(
        const h4* __restrict__ xpad4, const _Float16* __restrict__ wdf,
        const _Float16* __restrict__ wof, const float* __restrict__ b_off,
        const float* __restrict__ b_dc, float* __restrict__ out) {
    const int lane = threadIdx.x & 63;
    const int wid = __builtin_amdgcn_readfirstlane(threadIdx.x >> 6);
    const int p = lane & 15, g = lane >> 4;
    const int bid = blockIdx.x;
    const int tile = (bid & 7) * 72 + (bid >> 3);   // XCD swizzle (576 = 8*72)
    const int wt = tile * 4 + wid;                  // wave-tile 0..2303
    const int flat0 = wt * 16;
    const int b_u = __builtin_amdgcn_readfirstlane(flat0 / HW);
    const int loc0 = flat0 - b_u * HW;
    const int h = loc0 / W;                         // uniform per wave (16|96)
    const int w = loc0 % W + p;                     // my pixel's column

    __shared__ _Float16 wlds[WDF_HALFS];            // 73728 B deform weights
    __shared__ float offt[4][2 * KT][16];           // 4608 B wave-private slabs

    // ---- stage wdf -> LDS (once; drains at the pre-Phase-B barrier) ----
    // 72 segments of 1 KB (64 lanes x 16B, linear): dest = seg base + lane*16,
    // src per-lane — exactly global_load_lds's addressing model.
    {
        #pragma unroll
        for (int s2 = 0; s2 < 18; ++s2) {
            const int seg = wid * 18 + s2;
            __builtin_amdgcn_global_load_lds(
                (const __attribute__((address_space(1))) unsigned int*)
                    (wdf + (size_t)seg * 512 + lane * 8),
                (__attribute__((address_space(3))) unsigned int*)
                    &wlds[seg * 512],
                16, 0, 0);
        }
    }

    const h4* xq = xpad4 + (size_t)b_u * NQ * HPWP;

    // ---------------- Phase A: offset conv ----------------
    {
        f32x4 a0 = {0.f,0.f,0.f,0.f}, a1 = {0.f,0.f,0.f,0.f};
        half8 bf[2][2];                             // [set][ks]
        half8 wcA[4], wnA[4];                       // [2ks*2of] cur/next tap
        const _Float16* wofb = wof + lane * 8;

        auto loadWA = [&](half8* dst, int k) {
            #pragma unroll
            for (int ks = 0; ks < 2; ++ks) {
                dst[2 * ks]     = *(const half8*)(wofb + k * 1024 + ks * 512);
                dst[2 * ks + 1] = *(const half8*)(wofb + 9216 + k * 1024 + ks * 512);
            }
        };
        auto issueA = [&](int s, int k) {
            const int cell = (h + k / 3 - 1 + PAD) * WP + (w + k % 3 - 1 + PAD);
            #pragma unroll
            for (int ks = 0; ks < 2; ++ks) {
                h4 q0 = xq[(size_t)(ks * 8 + 2 * g)     * HPWP + cell];
                h4 q1 = xq[(size_t)(ks * 8 + 2 * g + 1) * HPWP + cell];
                bf[s][ks] = __builtin_shufflevector(q0, q1, 0,1,2,3,4,5,6,7);
            }
        };
        auto mfmaA = [&](int s, const half8* wa) {
            #pragma unroll
            for (int ks = 0; ks < 2; ++ks) {
                a0 = __builtin_amdgcn_mfma_f32_16x16x32_f16(wa[2*ks],   bf[s][ks], a0, 0, 0, 0);
                a1 = __builtin_amdgcn_mfma_f32_16x16x32_f16(wa[2*ks+1], bf[s][ks], a1, 0, 0, 0);
            }
        };

        loadWA(wcA, 0);
        issueA(0, 0); issueA(1, 1);
        #pragma unroll
        for (int k = 1; k <= 8; ++k) {
            loadWA(wnA, k);                         // tap-k weights, covered by mfma below
            __builtin_amdgcn_sched_barrier(0);
            mfmaA((k - 1) & 1, wcA);                // tap k-1
            __builtin_amdgcn_sched_barrier(0);
            if (k < 8) issueA((k - 1) & 1, k + 1);  // tap t lives in set t&1
            #pragma unroll
            for (int q2 = 0; q2 < 4; ++q2) wcA[q2] = wnA[q2];
        }
        mfmaA(0, wcA);                              // tap 8

        #pragma unroll
        for (int r = 0; r < 4; ++r) {               // oc 0..15
            const int oc = g * 4 + r;
            offt[wid][oc][p] = a0[r] + b_off[oc];
        }
        if (g == 0) {                               // oc 16,17
            #pragma unroll
            for (int r = 0; r < 2; ++r)
                offt[wid][16 + r][p] = a1[r] + b_off[16 + r];
        }
    }
    __syncthreads();    // drains wdf staging (vmcnt) + publishes wlds

    // ---------------- Phase B: deformable conv ----------------
    {
        f32x4 acc[4] = {{0.f,0.f,0.f,0.f},{0.f,0.f,0.f,0.f},
                        {0.f,0.f,0.f,0.f},{0.f,0.f,0.f,0.f}};
        h4x2 rt[2][2][2], rb[2][2][2];              // [set][ks][q2] top/bottom rows
        h4 Wc[2][4];                                // [set][corner] splats
        const _Float16* wl = wlds + lane * 8;       // my fragment column in LDS

        auto issueB = [&](int s, int k) {
            const float dy = offt[wid][2 * k][p];
            const float dx = offt[wid][2 * k + 1][p];
            const float py = (float)(h + k / 3 - 1) + dy;
            const float px = (float)(w + k % 3 - 1) + dx;
            const float y0f = floorf(py), x0f = floorf(px);
            const float ly = py - y0f, lx = px - x0f;
            int y0 = (int)y0f, x0 = (int)x0f;
            y0 = min(max(y0, -PAD), H + PAD - 2);   // clamp lands in zero halo
            x0 = min(max(x0, -PAD), W + PAD - 2);
            const int base = (y0 + PAD) * WP + (x0 + PAD);
            const float a11 = ly * lx;
            const _Float16 f11 = (_Float16)a11;
            const _Float16 f10 = (_Float16)(ly - a11);
            const _Float16 f01 = (_Float16)(lx - a11);
            const _Float16 f00 = (_Float16)(1.f - ly - lx + a11);
            #pragma unroll
            for (int e = 0; e < 4; ++e) { Wc[s][0][e] = f00; Wc[s][1][e] = f01;
                                          Wc[s][2][e] = f10; Wc[s][3][e] = f11; }
            #pragma unroll
            for (int ks = 0; ks < 2; ++ks) {
                #pragma unroll
                for (int q2 = 0; q2 < 2; ++q2) {
                    const h4* qp = xq + (size_t)(ks * 8 + 2 * g + q2) * HPWP + base;
                    __builtin_memcpy(&rt[s][ks][q2], qp, 16);        // (y0, x0..x0+1)
                    __builtin_memcpy(&rb[s][ks][q2], qp + WP, 16);   // (y0+1, ...)
                }
            }
        };
        auto mfmaB = [&](int s, int k) {
            #pragma unroll
            for (int ks = 0; ks < 2; ++ks) {
                h4 s0 = rt[s][ks][0].a * Wc[s][0] + rt[s][ks][0].b * Wc[s][1]
                      + rb[s][ks][0].a * Wc[s][2] + rb[s][ks][0].b * Wc[s][3];
                h4 s1 = rt[s][ks][1].a * Wc[s][0] + rt[s][ks][1].b * Wc[s][1]
                      + rb[s][ks][1].a * Wc[s][2] + rb[s][ks][1].b * Wc[s][3];
                half8 bfr = __builtin_shufflevector(s0, s1, 0,1,2,3,4,5,6,7);
                #pragma unroll
                for (int m = 0; m < 4; ++m) {
                    half8 wf = *(const half8*)(wl + m * 9216 + k * 1024 + ks * 512);
                    acc[m] = __builtin_amdgcn_mfma_f32_16x16x32_f16(wf, bfr,
                                                                    acc[m], 0, 0, 0);
                }
            }
        };

        issueB(0, 0); issueB(1, 1);
        #pragma unroll
        for (int k = 1; k <= 8; ++k) {
            __builtin_amdgcn_sched_barrier(0);
            mfmaB((k - 1) & 1, k - 1);
            __builtin_amdgcn_sched_barrier(0);
            if (k < 8) issueB((k - 1) & 1, k + 1);
        }
        mfmaB(0, 8);

        #pragma unroll
        for (int m = 0; m < 4; ++m) {
            #pragma unroll
            for (int r = 0; r < 4; ++r) {
                const int o = m * 16 + g * 4 + r;
                out[((size_t)b_u * C + o) * HW + loc0 + p] = acc[m][r] + b_dc[o];
            }
        }
    }
}

// ---------------------------------------------------------------------------
extern "C" void kernel_launch(void* const* d_in, const int* in_sizes, int n_in,
                              void* d_out, int out_size, void* d_ws, size_t ws_size,
                              hipStream_t stream) {
    const float* x     = (const float*)d_in[0];
    const float* w_off = (const float*)d_in[1];
    const float* b_off = (const float*)d_in[2];
    const float* w_dc  = (const float*)d_in[3];
    const float* b_dc  = (const float*)d_in[4];
    float* out = (float*)d_out;

    char* ws = (char*)d_ws;
    h4*        xpad4 = (h4*)ws;                            // 692224 * 8B = 5537792 B
    _Float16*  wdf   = (_Float16*)(ws + 5537792);          // 36864 h
    _Float16*  wof   = (_Float16*)(ws + 5537792 + 73728);  // 18432 h

    prep<<<B * NQ * HPWP / 256, 256, 0, stream>>>(x, w_off, w_dc, xpad4, wdf, wof);
    fused_wave<<<576, 256, 0, stream>>>(xpad4, wdf, wof, b_off, b_dc, out);
}